// Round 5
// baseline (348.306 us; speedup 1.0000x reference)
//
#include <hip/hip_runtime.h>
#include <math.h>

#define B_ 2
#define C_ 256
#define N_ 4096
#define TXT_ 512
#define CH_ 128
#define TN 32
#define GT 64
#define GK 32
#define KSPLIT 4
#define PXR 4224          // 64 * 66 padded-pixel rows per batch
#define PXPAD 96          // halo pad rows each side
#define PXTOT (PXR + 2 * PXPAD)

typedef unsigned short u16;
typedef __attribute__((ext_vector_type(8))) short short8;
typedef __attribute__((ext_vector_type(4))) float f32x4;

__device__ __forceinline__ float bf2f(u16 v){
  union { unsigned u; float f; } w; w.u = ((unsigned)v) << 16; return w.f;
}
__device__ __forceinline__ u16 f2bf(float f){
  union { float f; unsigned u; } w; w.f = f;
  unsigned r = w.u + 0x7fffu + ((w.u >> 16) & 1u);
  return (u16)(r >> 16);
}

#define MFMA_BF16(a,b,c) __builtin_amdgcn_mfma_f32_16x16x32_bf16(a,b,c,0,0,0)

// Stage a 128-row x 64-col bf16 tile from global (row stride `stride` elems) into
// LDS via global_load_lds (linear dest). Source addresses are pre-swizzled so the
// LDS holds the XOR-swizzled tile; frag_ld applies the same XOR on read.
__device__ __forceinline__ void stage_tile(const u16* __restrict__ g, int stride, u16* lds, int t)
{
  #pragma unroll
  for (int q = 0; q < 4; q++){
    int e = q * 256 + t;          // 16B unit index
    int row = e >> 3;             // 8 units per 128B row
    int slot = e & 7;
    const u16* gp = g + (size_t)row * stride + ((slot ^ (row & 7)) << 3);
    u16* lp = lds + (size_t)e * 8;
    __builtin_amdgcn_global_load_lds((const __attribute__((address_space(1))) void*)gp,
                                     (__attribute__((address_space(3))) void*)lp, 16, 0, 0);
  }
}

__device__ __forceinline__ short8 frag_ld(const u16* lds, int row, int slot)
{
  return *(const short8*)(lds + row * 64 + ((slot ^ (row & 7)) << 3));
}

// ---------- text pipeline: txt_emb, attn constant (v@wo^T+bo), txt_n ----------
__global__ __launch_bounds__(256) void k_text(
    const float* __restrict__ txt, const float* __restrict__ tpw,
    const float* __restrict__ tpb, const float* __restrict__ wv,
    const float* __restrict__ bv, const float* __restrict__ wo,
    const float* __restrict__ bo,
    float* __restrict__ txt_emb, float* __restrict__ attn_c, float* __restrict__ txt_n)
{
  int b = blockIdx.x, t = threadIdx.x;
  __shared__ float te[C_], vs[C_], red[C_];
  const float* tb = txt + b * TXT_;
  const float* wr = tpw + (size_t)t * TXT_;
  float s = 0.f;
  for (int j = 0; j < TXT_; j++) s += tb[j] * wr[j];
  s += tpb[t];
  te[t] = s;
  txt_emb[b * C_ + t] = s;
  __syncthreads();
  float sv = 0.f;
  const float* wvr = wv + (size_t)t * C_;
  for (int j = 0; j < C_; j++) sv += te[j] * wvr[j];
  sv += bv[t];
  vs[t] = sv;
  __syncthreads();
  float sa = 0.f;
  const float* wor = wo + (size_t)t * C_;
  for (int j = 0; j < C_; j++) sa += vs[j] * wor[j];
  sa += bo[t];
  attn_c[b * C_ + t] = sa;
  red[t] = te[t] * te[t];
  __syncthreads();
  for (int o = 128; o > 0; o >>= 1){ if (t < o) red[t] += red[t + o]; __syncthreads(); }
  float nrm = sqrtf(red[0]);
  float inv = 1.f / fmaxf(nrm, 1e-12f);
  txt_n[b * C_ + t] = te[t] * inv;
}

// ---------- source (residual+LN) -> srcT bf16 [C][N], snb bf16 [N][C], cos ----------
__global__ __launch_bounds__(256) void k_source(
    const float* __restrict__ img, const float* __restrict__ attn_c,
    const float* __restrict__ ln_g, const float* __restrict__ ln_b,
    const float* __restrict__ txt_n,
    u16* __restrict__ srcT, u16* __restrict__ snb, float* __restrict__ cosv)
{
  int b = blockIdx.y;
  int n0 = blockIdx.x * TN;
  int t = threadIdx.x;
  __shared__ float x[C_][TN + 1];
  __shared__ float ps[8][TN];
  __shared__ float ps2[8][TN];
  __shared__ float ac_s[C_], g_s[C_], bb_s[C_], tn_s[C_];
  __shared__ float mean_s[TN], rstd_s[TN], rn_s[TN];
  ac_s[t] = attn_c[b * C_ + t];
  g_s[t]  = ln_g[t];
  bb_s[t] = ln_b[t];
  tn_s[t] = txt_n[b * C_ + t];
  const float* ib = img + (size_t)b * C_ * N_ + n0;
  for (int k = 0; k < TN; k++){
    int e = t + k * 256;
    int c = e >> 5, nn = e & 31;
    x[c][nn] = ib[(size_t)c * N_ + nn];
  }
  __syncthreads();
  for (int k = 0; k < TN; k++){
    int e = t + k * 256;
    int c = e >> 5, nn = e & 31;
    x[c][nn] += ac_s[c];
  }
  __syncthreads();
  {
    int p = t >> 5, nn = t & 31;
    float s1 = 0.f, s2 = 0.f;
    for (int j = 0; j < 32; j++){
      float v = x[p + 8 * j][nn];
      s1 += v; s2 += v * v;
    }
    ps[p][nn] = s1; ps2[p][nn] = s2;
  }
  __syncthreads();
  if (t < TN){
    float S1 = 0.f, S2 = 0.f;
    for (int pp = 0; pp < 8; pp++){ S1 += ps[pp][t]; S2 += ps2[pp][t]; }
    float mean = S1 * (1.f / C_);
    float var = S2 * (1.f / C_) - mean * mean;
    mean_s[t] = mean;
    rstd_s[t] = rsqrtf(var + 1e-5f);
  }
  __syncthreads();
  for (int k = 0; k < TN; k++){
    float sval = (x[t][k] - mean_s[k]) * rstd_s[k] * g_s[t] + bb_s[t];
    x[t][k] = sval;
  }
  for (int kq = 0; kq < TN; kq += 4){
    ushort4 pkv;
    pkv.x = f2bf(x[t][kq + 0]);
    pkv.y = f2bf(x[t][kq + 1]);
    pkv.z = f2bf(x[t][kq + 2]);
    pkv.w = f2bf(x[t][kq + 3]);
    *reinterpret_cast<ushort4*>(&srcT[(size_t)(b * C_ + t) * N_ + n0 + kq]) = pkv;
  }
  __syncthreads();
  {
    int p = t >> 5, nn = t & 31;
    float s2 = 0.f, sd = 0.f;
    for (int j = 0; j < 32; j++){
      int c = p + 8 * j;
      float v = x[c][nn];
      s2 += v * v; sd += v * tn_s[c];
    }
    ps[p][nn] = s2; ps2[p][nn] = sd;
  }
  __syncthreads();
  if (t < TN){
    float S2 = 0.f, SD = 0.f;
    for (int pp = 0; pp < 8; pp++){ S2 += ps[pp][t]; SD += ps2[pp][t]; }
    float nrm = sqrtf(S2);
    float rn = 1.f / fmaxf(nrm, 1e-12f);
    rn_s[t] = rn;
    cosv[(b << 12) + n0 + t] = SD * rn;
  }
  __syncthreads();
  for (int k = 0; k < TN; k++){
    snb[(size_t)((b << 12) + n0 + k) * C_ + t] = f2bf(x[t][k] * rn_s[k]);
  }
}

// ---------- marginals ----------
__global__ __launch_bounds__(256) void k_qmarg(const float* __restrict__ dens, float* __restrict__ q){
  int b = blockIdx.x, t = threadIdx.x;
  __shared__ float red[256];
  const float* d = dens + (size_t)b * N_;
  float s = 0.f;
  for (int n = t; n < N_; n += 256) s += fmaxf(d[n], 0.f) + 1e-6f;
  red[t] = s; __syncthreads();
  for (int o = 128; o > 0; o >>= 1){ if (t < o) red[t] += red[t + o]; __syncthreads(); }
  float inv = 1.f / red[0];
  for (int n = t; n < N_; n += 256) q[b * N_ + n] = (fmaxf(d[n], 0.f) + 1e-6f) * inv;
}

__global__ __launch_bounds__(256) void k_pmarg(const float* __restrict__ cosv,
    const float* __restrict__ temp_p, float* __restrict__ p){
  int b = blockIdx.x, t = threadIdx.x;
  __shared__ float red[256];
  float temp = fmaxf(temp_p[0], 0.01f);
  float inv_t = 1.f / temp;
  const float* cb = cosv + (size_t)b * N_;
  float m = -1e30f;
  for (int n = t; n < N_; n += 256) m = fmaxf(m, cb[n] * inv_t);
  red[t] = m; __syncthreads();
  for (int o = 128; o > 0; o >>= 1){ if (t < o) red[t] = fmaxf(red[t], red[t + o]); __syncthreads(); }
  m = red[0]; __syncthreads();
  float s = 0.f;
  for (int n = t; n < N_; n += 256) s += expf(cb[n] * inv_t - m);
  red[t] = s; __syncthreads();
  for (int o = 128; o > 0; o >>= 1){ if (t < o) red[t] += red[t + o]; __syncthreads(); }
  float invs = 1.f / red[0];
  for (int n = t; n < N_; n += 256) p[b * N_ + n] = expf(cb[n] * inv_t - m) * invs;
}

__global__ __launch_bounds__(256) void k_zero(float* __restrict__ p, int n){
  int i = blockIdx.x * 256 + threadIdx.x;
  if (i < n) p[i] = 0.f;
}

// ---------- K = exp(20*(sn sn^T - 1)) bf16 via MFMA, SYMMETRIC ----------
// Grid over upper-triangular tile pairs (m0 <= n0); each block stores the direct
// tile (via row-major LDS Ct) AND the mirror tile (via Ct2, natural b64 packing of
// the column-major MFMA fragments). colsum gets col sums (direct) + row sums (mirror).
__global__ __launch_bounds__(256) void k_kgen(
    const u16* __restrict__ snb, u16* __restrict__ Kp, float* __restrict__ colsum)
{
  int b = blockIdx.y;
  // triangular decode: blockIdx.x in [0, 528) -> (a, bc) with bc <= a
  int kidx = blockIdx.x;
  int a = (int)((sqrtf(8.f * kidx + 1.f) - 1.f) * 0.5f);
  while ((a + 1) * (a + 2) / 2 <= kidx) a++;
  while (a * (a + 1) / 2 > kidx) a--;
  int bc = kidx - a * (a + 1) / 2;
  int n0 = a << 7, m0 = bc << 7;            // m0 <= n0
  bool diag = (m0 == n0);

  int t = threadIdx.x;
  int lane = t & 63, w = t >> 6;
  int wr = w >> 1, wc = w & 1;
  __shared__ __align__(16) u16 shbuf[128 * 128];    // Al|Bl during K-loop, then Ct
  __shared__ __align__(16) u16 Ct2[128 * 128];      // mirror tile (row-major in n-col idx)
  u16* Al = shbuf;
  u16* Bl = shbuf + 128 * 64;
  __shared__ float cs_col[128], cs_row[128];
  if (t < 128){ cs_col[t] = 0.f; cs_row[t] = 0.f; }
  f32x4 zero = {0.f, 0.f, 0.f, 0.f};
  f32x4 acc[4][4];
  #pragma unroll
  for (int i = 0; i < 4; i++){
    #pragma unroll
    for (int j = 0; j < 4; j++) acc[i][j] = zero;
  }
  const u16* sb = snb + (size_t)b * N_ * C_;
  const u16* ga = sb + (size_t)m0 * C_;
  const u16* gb = sb + (size_t)n0 * C_;
  for (int kt = 0; kt < C_; kt += 64){
    stage_tile(ga + kt, C_, Al, t);
    stage_tile(gb + kt, C_, Bl, t);
    __syncthreads();
    #pragma unroll
    for (int kh = 0; kh < 2; kh++){
      short8 af[4], bfv[4];
      #pragma unroll
      for (int i = 0; i < 4; i++){
        af[i]  = frag_ld(Al, wr * 64 + i * 16 + (lane & 15), kh * 4 + (lane >> 4));
        bfv[i] = frag_ld(Bl, wc * 64 + i * 16 + (lane & 15), kh * 4 + (lane >> 4));
      }
      #pragma unroll
      for (int i = 0; i < 4; i++){
        #pragma unroll
        for (int j = 0; j < 4; j++)
          acc[i][j] = MFMA_BF16(af[i], bfv[j], acc[i][j]);
      }
    }
    __syncthreads();
  }
  // epilogue: exp -> bf16; Ct (row-major, swizzled) for direct tile, Ct2 for mirror
  u16* Ct = shbuf;
  float rsum[16];
  #pragma unroll
  for (int q = 0; q < 16; q++) rsum[q] = 0.f;
  #pragma unroll
  for (int j = 0; j < 4; j++){
    int col = wc * 64 + j * 16 + (lane & 15);
    float csum = 0.f;
    #pragma unroll
    for (int i = 0; i < 4; i++){
      int rb = wr * 64 + i * 16 + (lane >> 4) * 4;
      ushort4 pk4;
      #pragma unroll
      for (int r = 0; r < 4; r++){
        float e = expf(20.f * (acc[i][j][r] - 1.f));
        u16 pk = f2bf(e);
        float ev = bf2f(pk);
        csum += ev;
        rsum[i * 4 + r] += ev;
        int row = rb + r;
        Ct[row * 128 + ((((col >> 3) ^ (row & 7)) << 3) | (col & 7))] = pk;
        ((u16*)&pk4)[r] = pk;
      }
      if (!diag){
        int a2 = col * 128 + ((((rb >> 3) ^ (col & 7)) << 3) | (rb & 7));
        *reinterpret_cast<ushort4*>(&Ct2[a2]) = pk4;
      }
    }
    atomicAdd(&cs_col[col], csum);
  }
  if (!diag){
    #pragma unroll
    for (int q = 0; q < 16; q++){
      float v = rsum[q];
      v += __shfl_xor(v, 1); v += __shfl_xor(v, 2);
      v += __shfl_xor(v, 4); v += __shfl_xor(v, 8);
      if ((lane & 15) == 0){
        int row = wr * 64 + (q >> 2) * 16 + (lane >> 4) * 4 + (q & 3);
        atomicAdd(&cs_row[row], v);
      }
    }
  }
  __syncthreads();
  u16* Kb = Kp + (size_t)b * N_ * N_;
  // direct tile: coalesced 16B stores
  for (int e = t; e < 2048; e += 256){
    int row = e >> 4, un = e & 15;
    short8 v8 = *(const short8*)(Ct + row * 128 + ((un ^ (row & 7)) << 3));
    *reinterpret_cast<short8*>(&Kb[(size_t)(m0 + row) * N_ + n0 + (un << 3)]) = v8;
  }
  if (!diag){
    for (int e = t; e < 2048; e += 256){
      int c = e >> 4, un = e & 15;
      short8 v8 = *(const short8*)(Ct2 + c * 128 + ((un ^ (c & 7)) << 3));
      *reinterpret_cast<short8*>(&Kb[(size_t)(n0 + c) * N_ + m0 + (un << 3)]) = v8;
    }
  }
  if (t < 128){
    atomicAdd(&colsum[b * N_ + n0 + t], cs_col[t]);
    if (!diag) atomicAdd(&colsum[b * N_ + m0 + t], cs_row[t]);
  }
}

__global__ __launch_bounds__(256) void k_div(
    const float* __restrict__ marg, const float* __restrict__ denom, float* __restrict__ outp){
  int i = blockIdx.x * 256 + threadIdx.x;
  if (i < B_ * N_) outp[i] = marg[i] / (denom[i] + 1e-8f);
}

// ---------- out[r] = marg[r] / (K_row_r . x + 1e-8)  (K symmetric), 8 rows/block ----------
__global__ __launch_bounds__(256) void k_mv(
    const u16* __restrict__ Kp, const float* __restrict__ x,
    const float* __restrict__ marg, float* __restrict__ outp)
{
  int r0 = blockIdx.x * 8;
  int b = r0 >> 12;
  int t = threadIdx.x, w = t >> 6, lane = t & 63;
  __shared__ __align__(16) float xs[N_];
  const float* xb = x + b * N_;
  for (int i = t; i < N_ / 4; i += 256)
    reinterpret_cast<float4*>(xs)[i] = reinterpret_cast<const float4*>(xb)[i];
  __syncthreads();
  int r = r0 + w * 2;
  const u16* Kr0 = Kp + (size_t)b * N_ * N_ + (size_t)(r & (N_ - 1)) * N_;
  const u16* Kr1 = Kr0 + N_;
  float acc0 = 0.f, acc1 = 0.f;
  #pragma unroll
  for (int p = 0; p < 8; p++){
    int idx = p * 512 + lane * 8;
    short8 k0 = *reinterpret_cast<const short8*>(Kr0 + idx);
    short8 k1 = *reinterpret_cast<const short8*>(Kr1 + idx);
    float4 x0 = *reinterpret_cast<const float4*>(xs + idx);
    float4 x1 = *reinterpret_cast<const float4*>(xs + idx + 4);
    acc0 += bf2f((u16)k0[0]) * x0.x + bf2f((u16)k0[1]) * x0.y
          + bf2f((u16)k0[2]) * x0.z + bf2f((u16)k0[3]) * x0.w
          + bf2f((u16)k0[4]) * x1.x + bf2f((u16)k0[5]) * x1.y
          + bf2f((u16)k0[6]) * x1.z + bf2f((u16)k0[7]) * x1.w;
    acc1 += bf2f((u16)k1[0]) * x0.x + bf2f((u16)k1[1]) * x0.y
          + bf2f((u16)k1[2]) * x0.z + bf2f((u16)k1[3]) * x0.w
          + bf2f((u16)k1[4]) * x1.x + bf2f((u16)k1[5]) * x1.y
          + bf2f((u16)k1[6]) * x1.z + bf2f((u16)k1[7]) * x1.w;
  }
  for (int o = 32; o > 0; o >>= 1){
    acc0 += __shfl_down(acc0, o);
    acc1 += __shfl_down(acc1, o);
  }
  if (lane == 0){
    outp[r] = marg[r] / (acc0 + 1e-8f);
    outp[r + 1] = marg[r + 1] / (acc1 + 1e-8f);
  }
}

// ---------- usrcT[c][n] = srcT[c][n] * u[n] ----------
__global__ __launch_bounds__(256) void k_uscale(
    const u16* __restrict__ srcT, const float* __restrict__ uu, u16* __restrict__ usrcT)
{
  int i = blockIdx.x * 256 + threadIdx.x;
  int n8 = i & (N_ / 8 - 1);
  int row = i >> 9;
  int b = row >> 8;
  const u16* s = srcT + (size_t)row * N_ + n8 * 8;
  short8 v = *reinterpret_cast<const short8*>(s);
  const float* ub = uu + b * N_ + n8 * 8;
  short8 o;
  #pragma unroll
  for (int q = 0; q < 8; q++) o[q] = (short)f2bf(bf2f((u16)v[q]) * ub[q]);
  *reinterpret_cast<short8*>(usrcT + (size_t)row * N_ + n8 * 8) = o;
}

// ---------- part[ks][m][c] = sum_{n in ks chunk} K[m][n] * usrc[n][c]  (MFMA, bf16 out) ----------
__global__ __launch_bounds__(256) void k_full(
    const u16* __restrict__ Kp, const u16* __restrict__ usrcT,
    u16* __restrict__ p0, u16* __restrict__ p1,
    u16* __restrict__ p2, u16* __restrict__ p3)
{
  int m0 = blockIdx.x << 7;
  int c0 = blockIdx.y << 7;
  int b = blockIdx.z >> 2, ks = blockIdx.z & 3;
  int t = threadIdx.x, lane = t & 63, w = t >> 6;
  int wr = w >> 1, wc = w & 1;
  __shared__ __align__(16) u16 shbuf[128 * 128];   // Al|Bl, then Ct restage
  u16* Al = shbuf;
  u16* Bl = shbuf + 128 * 64;
  f32x4 zero = {0.f, 0.f, 0.f, 0.f};
  f32x4 acc[4][4];
  #pragma unroll
  for (int i = 0; i < 4; i++){
    #pragma unroll
    for (int j = 0; j < 4; j++) acc[i][j] = zero;
  }
  const u16* ka = Kp + (size_t)b * N_ * N_ + (size_t)m0 * N_ + ks * (N_ / KSPLIT);
  const u16* ub = usrcT + (size_t)b * C_ * N_ + (size_t)c0 * N_ + ks * (N_ / KSPLIT);
  for (int kt = 0; kt < N_ / KSPLIT; kt += 64){
    stage_tile(ka + kt, N_, Al, t);
    stage_tile(ub + kt, N_, Bl, t);
    __syncthreads();
    #pragma unroll
    for (int kh = 0; kh < 2; kh++){
      short8 af[4], bfv[4];
      #pragma unroll
      for (int i = 0; i < 4; i++){
        af[i]  = frag_ld(Al, wr * 64 + i * 16 + (lane & 15), kh * 4 + (lane >> 4));
        bfv[i] = frag_ld(Bl, wc * 64 + i * 16 + (lane & 15), kh * 4 + (lane >> 4));
      }
      #pragma unroll
      for (int i = 0; i < 4; i++){
        #pragma unroll
        for (int j = 0; j < 4; j++)
          acc[i][j] = MFMA_BF16(af[i], bfv[j], acc[i][j]);
      }
    }
    __syncthreads();
  }
  // restage output tile [128 m][128 c] as bf16 in LDS, then coalesced stores
  u16* Ct = shbuf;
  #pragma unroll
  for (int j = 0; j < 4; j++){
    int col = wc * 64 + j * 16 + (lane & 15);
    #pragma unroll
    for (int i = 0; i < 4; i++){
      int rb = wr * 64 + i * 16 + (lane >> 4) * 4;
      #pragma unroll
      for (int r = 0; r < 4; r++){
        int row = rb + r;
        Ct[row * 128 + ((((col >> 3) ^ (row & 7)) << 3) | (col & 7))] = f2bf(acc[i][j][r]);
      }
    }
  }
  __syncthreads();
  u16* P = (ks == 0) ? p0 : (ks == 1) ? p1 : (ks == 2) ? p2 : p3;
  for (int e = t; e < 2048; e += 256){
    int row = e >> 4, un = e & 15;
    short8 v8 = *(const short8*)(Ct + row * 128 + ((un ^ (row & 7)) << 3));
    *reinterpret_cast<short8*>(&P[(size_t)((b << 12) + m0 + row) * C_ + c0 + (un << 3)]) = v8;
  }
}

// ---------- out_feat = img + 1x1conv(vv * (p0+p1+p2+p3)) ----------
__global__ __launch_bounds__(256) void k_opconv(
    const float* __restrict__ opw, const float* __restrict__ opb,
    const u16* __restrict__ p0, const u16* __restrict__ p1,
    const u16* __restrict__ p2, const u16* __restrict__ p3,
    const float* __restrict__ vvv,
    const float* __restrict__ img, float* __restrict__ outf)
{
  int b = blockIdx.z;
  int n0 = blockIdx.x * GT;
  int co0 = blockIdx.y * GT;
  int t = threadIdx.x, tx = t & 15, ty = t >> 4;
  __shared__ __align__(16) float Ws[GK][68];
  __shared__ __align__(16) float Fs[GK][68];
  __shared__ float vs_n[GT];
  if (t < GT) vs_n[t] = vvv[b * N_ + n0 + t];
  __syncthreads();
  float acc[4][4] = {};
  for (int c0 = 0; c0 < C_; c0 += GK){
    for (int e = t; e < GT * GK; e += 256){
      int a_ = e >> 5, i_ = e & 31;
      Ws[i_][a_] = opw[(size_t)(co0 + a_) * C_ + c0 + i_];
      size_t idx = (size_t)((b << 12) + n0 + a_) * C_ + c0 + i_;
      Fs[i_][a_] = (bf2f(p0[idx]) + bf2f(p1[idx]) + bf2f(p2[idx]) + bf2f(p3[idx])) * vs_n[a_];
    }
    __syncthreads();
    #pragma unroll
    for (int kk = 0; kk < GK; kk++){
      float4 a4 = *reinterpret_cast<const float4*>(&Ws[kk][ty * 4]);
      float4 b4 = *reinterpret_cast<const float4*>(&Fs[kk][tx * 4]);
      float ar[4] = {a4.x, a4.y, a4.z, a4.w};
      float br[4] = {b4.x, b4.y, b4.z, b4.w};
      #pragma unroll
      for (int i = 0; i < 4; i++)
        #pragma unroll
        for (int j = 0; j < 4; j++)
          acc[i][j] += ar[i] * br[j];
    }
    __syncthreads();
  }
  for (int i = 0; i < 4; i++){
    int co = co0 + ty * 4 + i;
    const float4 iv = *reinterpret_cast<const float4*>(&img[(size_t)(b * C_ + co) * N_ + n0 + tx * 4]);
    float ob = opb[co];
    float4 o;
    o.x = iv.x + acc[i][0] + ob; o.y = iv.y + acc[i][1] + ob;
    o.z = iv.z + acc[i][2] + ob; o.w = iv.w + acc[i][3] + ob;
    *reinterpret_cast<float4*>(&outf[(size_t)(b * C_ + co) * N_ + n0 + tx * 4]) = o;
  }
}

// ---------- transpose out_feat -> padded bf16 [b][px'][ci] ----------
__global__ __launch_bounds__(256) void k_tr(const float* __restrict__ outf, u16* __restrict__ inTp)
{
  int b = blockIdx.z;
  int c0 = blockIdx.y << 6;
  int px0 = blockIdx.x << 6;
  int t = threadIdx.x;
  __shared__ float tile[64][65];
  int tx = t & 63, ty4 = t >> 6;
  for (int cc = ty4; cc < 64; cc += 4)
    tile[cc][tx] = outf[((size_t)(b * C_) + c0 + cc) * N_ + px0 + tx];
  __syncthreads();
  int p = t >> 2, cg = (t & 3) << 4;
  int px = px0 + p;
  int y = px >> 6, x = px & 63;
  int pxp = y * 66 + x + 1;
  u16* dst = inTp + ((size_t)b * PXTOT + PXPAD + pxp) * C_ + c0 + cg;
  #pragma unroll
  for (int q = 0; q < 16; q += 4){
    ushort4 pk;
    pk.x = f2bf(tile[cg + q + 0][p]);
    pk.y = f2bf(tile[cg + q + 1][p]);
    pk.z = f2bf(tile[cg + q + 2][p]);
    pk.w = f2bf(tile[cg + q + 3][p]);
    *reinterpret_cast<ushort4*>(dst + q) = pk;
  }
}

// ---------- weights -> Wt[tap][co(256 fused)][ci] bf16, fused bias ----------
__global__ __launch_bounds__(256) void k_wtr(
    const float* __restrict__ hm1_w, const float* __restrict__ hv1_w,
    const float* __restrict__ hm1_b, const float* __restrict__ hv1_b,
    u16* __restrict__ Wt, float* __restrict__ biasF)
{
  int i = blockIdx.x * 256 + threadIdx.x;   // < 9*256*256
  int ci = i & 255, co = (i >> 8) & 255, tap = i >> 16;
  float v = (co < CH_) ? hm1_w[((size_t)co * C_ + ci) * 9 + tap]
                       : hv1_w[((size_t)(co - CH_) * C_ + ci) * 9 + tap];
  Wt[i] = f2bf(v);
  if (i < CH_) biasF[i] = hm1_b[i];
  else if (i < 2 * CH_) biasF[i] = hv1_b[i - CH_];
}

// ---------- fused 3x3 conv (both heads) as implicit GEMM: C[co][px'] (bf16 out) ----------
__global__ __launch_bounds__(256) void k_conv3m(
    const u16* __restrict__ inTp, const u16* __restrict__ Wt,
    const float* __restrict__ biasF,
    u16* __restrict__ q0, u16* __restrict__ q1,
    u16* __restrict__ q2, u16* __restrict__ q3)
{
  int px0 = blockIdx.x << 7;           // 0..32 (33 tiles of 128 px')
  int cot = blockIdx.y;                // 0..1 (co halves of 256 fused)
  int b = blockIdx.z >> 2, ks = blockIdx.z & 3;
  int t = threadIdx.x, lane = t & 63, w = t >> 6;
  int wr = w >> 1, wc = w & 1;
  __shared__ __align__(16) u16 Al[128 * 64];   // weights: 128 co rows x 64 ci
  __shared__ __align__(16) u16 Bl[128 * 64];   // input:   128 px rows x 64 ci
  f32x4 zero = {0.f, 0.f, 0.f, 0.f};
  f32x4 acc[4][4];
  #pragma unroll
  for (int i = 0; i < 4; i++){
    #pragma unroll
    for (int j = 0; j < 4; j++) acc[i][j] = zero;
  }
  const u16* inb = inTp + ((size_t)b * PXTOT + PXPAD + px0) * C_;
  for (int s = ks * 9; s < ks * 9 + 9; s++){
    int tap = s >> 2, cic = (s & 3) << 6;
    int ky = tap / 3, kx = tap - ky * 3;
    int off = (ky - 1) * 66 + (kx - 1);
    stage_tile(Wt + ((size_t)tap * 256 + cot * 128) * C_ + cic, C_, Al, t);
    stage_tile(inb + (ptrdiff_t)off * C_ + cic, C_, Bl, t);
    __syncthreads();
    #pragma unroll
    for (int kh = 0; kh < 2; kh++){
      short8 af[4], bfv[4];
      #pragma unroll
      for (int i = 0; i < 4; i++){
        af[i]  = frag_ld(Al, wr * 64 + i * 16 + (lane & 15), kh * 4 + (lane >> 4));
        bfv[i] = frag_ld(Bl, wc * 64 + i * 16 + (lane & 15), kh * 4 + (lane >> 4));
      }
      #pragma unroll
      for (int i = 0; i < 4; i++){
        #pragma unroll
        for (int j = 0; j < 4; j++)
          acc[i][j] = MFMA_BF16(af[i], bfv[j], acc[i][j]);
      }
    }
    __syncthreads();
  }
  u16* P = (ks == 0) ? q0 : (ks == 1) ? q1 : (ks == 2) ? q2 : q3;
  #pragma unroll
  for (int i = 0; i < 4; i++){
    #pragma unroll
    for (int j = 0; j < 4; j++){
      int pxp = px0 + wc * 64 + j * 16 + (lane & 15);
      int y = pxp / 66;
      int xm = pxp - y * 66;
      bool valid = (xm >= 1 && xm <= 64);
      int outn = y * 64 + xm - 1;
      #pragma unroll
      for (int r = 0; r < 4; r++){
        int co = cot * 128 + wr * 64 + i * 16 + (lane >> 4) * 4 + r;
        if (valid){
          float bco = (ks == 0) ? biasF[co] : 0.f;
          P[((size_t)(b * 256 + co)) * N_ + outn] = f2bf(acc[i][j][r] + bco);
        }
      }
    }
  }
}

// ---------- batchnorm stats over (B,H,W) per fused channel (sums 4 K-parts) ----------
__global__ __launch_bounds__(256) void k_bnstats2(
    const u16* __restrict__ p0, const u16* __restrict__ p1,
    const u16* __restrict__ p2, const u16* __restrict__ p3,
    float* __restrict__ stats)
{
  int ch = blockIdx.x, t = threadIdx.x;   // ch in [0,256)
  __shared__ float r1[256], r2[256];
  float s1 = 0.f, s2 = 0.f;
  for (int i = t; i < B_ * N_; i += 256){
    int b = i >> 12, n = i & (N_ - 1);
    size_t idx = ((size_t)(b * 256 + ch)) * N_ + n;
    float v = bf2f(p0[idx]) + bf2f(p1[idx]) + bf2f(p2[idx]) + bf2f(p3[idx]);
    s1 += v; s2 += v * v;
  }
  r1[t] = s1; r2[t] = s2; __syncthreads();
  for (int o = 128; o > 0; o >>= 1){
    if (t < o){ r1[t] += r1[t + o]; r2[t] += r2[t + o]; }
    __syncthreads();
  }
  if (t == 0){
    float mean = r1[0] / (float)(B_ * N_);
    float var = r2[0] / (float)(B_ * N_) - mean * mean;
    stats[ch * 2] = mean;
    stats[ch * 2 + 1] = rsqrtf(var + 1e-5f);
  }
}

// ---------- relu(bn(mid)) -> 1x1 conv to 2 channels (per head, choff) ----------
__global__ __launch_bounds__(256) void k_head2(
    const u16* __restrict__ p0, const u16* __restrict__ p1,
    const u16* __restrict__ p2, const u16* __restrict__ p3,
    const float* __restrict__ stats,
    const float* __restrict__ g, const float* __restrict__ bb,
    const float* __restrict__ w2, const float* __restrict__ b2,
    float* __restrict__ outp, int choff)
{
  int idx = blockIdx.x * 256 + threadIdx.x;
  int b = idx >> 12, n = idx & (N_ - 1);
  float a0 = 0.f, a1 = 0.f;
  for (int ch = 0; ch < CH_; ch++){
    int fc = choff + ch;
    size_t id = ((size_t)(b * 256 + fc)) * N_ + n;
    float v = bf2f(p0[id]) + bf2f(p1[id]) + bf2f(p2[id]) + bf2f(p3[id]);
    float rr = (v - stats[fc * 2]) * stats[fc * 2 + 1] * g[ch] + bb[ch];
    rr = fmaxf(rr, 0.f);
    a0 += w2[ch] * rr;
    a1 += w2[CH_ + ch] * rr;
  }
  outp[(size_t)(b * 2) * N_ + n] = a0 + b2[0];
  outp[(size_t)(b * 2 + 1) * N_ + n] = a1 + b2[1];
}

extern "C" void kernel_launch(void* const* d_in, const int* in_sizes, int n_in,
                              void* d_out, int out_size, void* d_ws, size_t ws_size,
                              hipStream_t stream)
{
  const float* img   = (const float*)d_in[0];
  const float* txt   = (const float*)d_in[1];
  const float* dens  = (const float*)d_in[2];
  const float* tp_w  = (const float*)d_in[3];
  const float* tp_b  = (const float*)d_in[4];
  const float* wv    = (const float*)d_in[9];
  const float* bv    = (const float*)d_in[10];
  const float* wo    = (const float*)d_in[11];
  const float* bo    = (const float*)d_in[12];
  const float* ln_g  = (const float*)d_in[13];
  const float* ln_b  = (const float*)d_in[14];
  const float* op_w  = (const float*)d_in[15];
  const float* op_b  = (const float*)d_in[16];
  const float* hm1_w = (const float*)d_in[17];
  const float* hm1_b = (const float*)d_in[18];
  const float* hm_g  = (const float*)d_in[19];
  const float* hm_b  = (const float*)d_in[20];
  const float* hm2_w = (const float*)d_in[21];
  const float* hm2_b = (const float*)d_in[22];
  const float* hv1_w = (const float*)d_in[23];
  const float* hv1_b = (const float*)d_in[24];
  const float* hv_g  = (const float*)d_in[25];
  const float* hv_b  = (const float*)d_in[26];
  const float* hv2_w = (const float*)d_in[27];
  const float* hv2_b = (const float*)d_in[28];
  const float* temp  = (const float*)d_in[29];

  char* wsb = (char*)d_ws;
  size_t off = 0;
  auto alloc = [&](size_t bytes) -> void* {
    void* p = wsb + off;
    off += (bytes + 255) & ~(size_t)255;
    return p;
  };
  u16*   Km     = (u16*)  alloc((size_t)B_ * N_ * N_ * sizeof(u16));   // 67.1 MB
  u16*   snb16  = (u16*)  alloc((size_t)B_ * N_ * C_ * sizeof(u16));   // 4.19 MB (part0 alias)
  u16*   srcT16 = (u16*)  alloc((size_t)B_ * C_ * N_ * sizeof(u16));   // 4.19 MB
  u16*   usrcT  = (u16*)  alloc((size_t)B_ * C_ * N_ * sizeof(u16));   // 4.19 MB
  u16*   part1  = (u16*)  alloc((size_t)B_ * N_ * C_ * sizeof(u16));   // 4.19 MB
  u16*   part2  = (u16*)  alloc((size_t)B_ * N_ * C_ * sizeof(u16));   // 4.19 MB
  u16*   part3  = (u16*)  alloc((size_t)B_ * N_ * C_ * sizeof(u16));   // 4.19 MB
  u16*   inTp   = (u16*)  alloc((size_t)B_ * PXTOT * C_ * sizeof(u16));// 4.52 MB
  u16*   Wt     = (u16*)  alloc((size_t)9 * 256 * C_ * sizeof(u16));   // 1.18 MB
  float* biasF  = (float*)alloc(256 * sizeof(float));
  float* txt_emb= (float*)alloc(B_ * C_ * sizeof(float));
  float* attn_c = (float*)alloc(B_ * C_ * sizeof(float));
  float* txt_n  = (float*)alloc(B_ * C_ * sizeof(float));
  float* cosv   = (float*)alloc(B_ * N_ * sizeof(float));
  float* qm     = (float*)alloc(B_ * N_ * sizeof(float));
  float* pm     = (float*)alloc(B_ * N_ * sizeof(float));
  float* uu     = (float*)alloc(B_ * N_ * sizeof(float));
  float* vvv    = (float*)alloc(B_ * N_ * sizeof(float));
  float* colsum = (float*)alloc(B_ * N_ * sizeof(float));
  float* stats  = (float*)alloc(256 * 2 * sizeof(float));

  // alias: part0 over snb16 (both 4.19 MB; snb dead after kgen, part0 written by k_full)
  u16* part0 = snb16;

  float* outf  = (float*)d_out;
  float* outhm = outf + (size_t)B_ * C_ * N_;
  float* outhv = outhm + (size_t)B_ * 2 * N_;

  k_text<<<B_, 256, 0, stream>>>(txt, tp_w, tp_b, wv, bv, wo, bo, txt_emb, attn_c, txt_n);
  k_source<<<dim3(N_ / TN, B_), 256, 0, stream>>>(img, attn_c, ln_g, ln_b, txt_n, srcT16, snb16, cosv);
  k_qmarg<<<B_, 256, 0, stream>>>(dens, qm);
  k_pmarg<<<B_, 256, 0, stream>>>(cosv, temp, pm);
  k_zero<<<(B_ * N_ + 255) / 256, 256, 0, stream>>>(colsum, B_ * N_);
  // conv prep with no deps on GEMM chain: weight transpose + zero padded input buffer
  k_wtr<<<9 * 256, 256, 0, stream>>>(hm1_w, hv1_w, hm1_b, hv1_b, Wt, biasF);
  k_zero<<<((int)((size_t)B_ * PXTOT * C_ / 2) + 255) / 256, 256, 0, stream>>>((float*)inTp, (int)((size_t)B_ * PXTOT * C_ / 2));
  // symmetric K generation: 528 upper-triangular tile pairs per batch
  k_kgen<<<dim3(528, B_), 256, 0, stream>>>(snb16, Km, colsum);
  // Sinkhorn (K symmetric: K^T x == K x)
  k_div<<<(B_ * N_ + 255) / 256, 256, 0, stream>>>(qm, colsum, vvv);        // vv1
  k_mv<<<B_ * N_ / 8, 256, 0, stream>>>(Km, vvv, pm, uu);                   // u1
  k_mv<<<B_ * N_ / 8, 256, 0, stream>>>(Km, uu, qm, vvv);                   // vv2
  k_mv<<<B_ * N_ / 8, 256, 0, stream>>>(Km, vvv, pm, uu);                   // u2
  k_mv<<<B_ * N_ / 8, 256, 0, stream>>>(Km, uu, qm, vvv);                   // vv3
  k_mv<<<B_ * N_ / 8, 256, 0, stream>>>(Km, vvv, pm, uu);                   // u3
  k_uscale<<<(B_ * C_ * N_ / 8 + 255) / 256, 256, 0, stream>>>(srcT16, uu, usrcT);
  k_full<<<dim3(N_ / 128, C_ / 128, B_ * KSPLIT), 256, 0, stream>>>(Km, usrcT, part0, part1, part2, part3);
  k_opconv<<<dim3(N_ / GT, C_ / GT, B_), 256, 0, stream>>>(op_w, op_b, part0, part1, part2, part3, vvv, img, outf);
  // fused heads: transpose -> implicit-GEMM conv (both heads) -> BN stats -> heads
  k_tr<<<dim3(N_ / 64, 4, B_), 256, 0, stream>>>(outf, inTp);
  k_conv3m<<<dim3(33, 2, B_ * KSPLIT), 256, 0, stream>>>(inTp, Wt, biasF, part0, part1, part2, part3);
  k_bnstats2<<<256, 256, 0, stream>>>(part0, part1, part2, part3, stats);
  k_head2<<<B_ * N_ / 256, 256, 0, stream>>>(part0, part1, part2, part3, stats, hm_g, hm_b, hm2_w, hm2_b, outhm, 0);
  k_head2<<<B_ * N_ / 256, 256, 0, stream>>>(part0, part1, part2, part3, stats, hv_g, hv_b, hv2_w, hv2_b, outhv, CH_);
}

// Round 6
// 343.243 us; speedup vs baseline: 1.0148x; 1.0148x over previous
//
#include <hip/hip_runtime.h>
#include <math.h>

#define B_ 2
#define C_ 256
#define N_ 4096
#define TXT_ 512
#define CH_ 128
#define TN 32
#define GT 64
#define GK 32
#define KSPLIT 4
#define PXR 4224          // 64 * 66 padded-pixel rows per batch
#define PXPAD 96          // halo pad rows each side
#define PXTOT (PXR + 2 * PXPAD)

typedef unsigned short u16;
typedef __attribute__((ext_vector_type(8))) short short8;
typedef __attribute__((ext_vector_type(4))) float f32x4;

__device__ __forceinline__ float bf2f(u16 v){
  union { unsigned u; float f; } w; w.u = ((unsigned)v) << 16; return w.f;
}
__device__ __forceinline__ u16 f2bf(float f){
  union { float f; unsigned u; } w; w.f = f;
  unsigned r = w.u + 0x7fffu + ((w.u >> 16) & 1u);
  return (u16)(r >> 16);
}

#define MFMA_BF16(a,b,c) __builtin_amdgcn_mfma_f32_16x16x32_bf16(a,b,c,0,0,0)

// Stage a 128-row x 64-col bf16 tile (256 threads). Pre-swizzled source, linear LDS dest.
__device__ __forceinline__ void stage_tile(const u16* __restrict__ g, int stride, u16* lds, int t)
{
  #pragma unroll
  for (int q = 0; q < 4; q++){
    int e = q * 256 + t;          // 16B unit index
    int row = e >> 3;
    int slot = e & 7;
    const u16* gp = g + (size_t)row * stride + ((slot ^ (row & 7)) << 3);
    u16* lp = lds + (size_t)e * 8;
    __builtin_amdgcn_global_load_lds((const __attribute__((address_space(1))) void*)gp,
                                     (__attribute__((address_space(3))) void*)lp, 16, 0, 0);
  }
}

// 512-thread variants: 128 rows and 256 rows.
__device__ __forceinline__ void stage_tile512_128(const u16* __restrict__ g, int stride, u16* lds, int t)
{
  #pragma unroll
  for (int q = 0; q < 2; q++){
    int e = q * 512 + t;          // 1024 units
    int row = e >> 3;
    int slot = e & 7;
    const u16* gp = g + (size_t)row * stride + ((slot ^ (row & 7)) << 3);
    u16* lp = lds + (size_t)e * 8;
    __builtin_amdgcn_global_load_lds((const __attribute__((address_space(1))) void*)gp,
                                     (__attribute__((address_space(3))) void*)lp, 16, 0, 0);
  }
}
__device__ __forceinline__ void stage_tile512_256(const u16* __restrict__ g, int stride, u16* lds, int t)
{
  #pragma unroll
  for (int q = 0; q < 4; q++){
    int e = q * 512 + t;          // 2048 units
    int row = e >> 3;
    int slot = e & 7;
    const u16* gp = g + (size_t)row * stride + ((slot ^ (row & 7)) << 3);
    u16* lp = lds + (size_t)e * 8;
    __builtin_amdgcn_global_load_lds((const __attribute__((address_space(1))) void*)gp,
                                     (__attribute__((address_space(3))) void*)lp, 16, 0, 0);
  }
}

__device__ __forceinline__ short8 frag_ld(const u16* lds, int row, int slot)
{
  return *(const short8*)(lds + row * 64 + ((slot ^ (row & 7)) << 3));
}

// ---------- text pipeline: txt_emb, attn constant (v@wo^T+bo), txt_n ----------
__global__ __launch_bounds__(256) void k_text(
    const float* __restrict__ txt, const float* __restrict__ tpw,
    const float* __restrict__ tpb, const float* __restrict__ wv,
    const float* __restrict__ bv, const float* __restrict__ wo,
    const float* __restrict__ bo,
    float* __restrict__ txt_emb, float* __restrict__ attn_c, float* __restrict__ txt_n)
{
  int b = blockIdx.x, t = threadIdx.x;
  __shared__ float te[C_], vs[C_], red[C_];
  const float* tb = txt + b * TXT_;
  const float* wr = tpw + (size_t)t * TXT_;
  float s = 0.f;
  for (int j = 0; j < TXT_; j++) s += tb[j] * wr[j];
  s += tpb[t];
  te[t] = s;
  txt_emb[b * C_ + t] = s;
  __syncthreads();
  float sv = 0.f;
  const float* wvr = wv + (size_t)t * C_;
  for (int j = 0; j < C_; j++) sv += te[j] * wvr[j];
  sv += bv[t];
  vs[t] = sv;
  __syncthreads();
  float sa = 0.f;
  const float* wor = wo + (size_t)t * C_;
  for (int j = 0; j < C_; j++) sa += vs[j] * wor[j];
  sa += bo[t];
  attn_c[b * C_ + t] = sa;
  red[t] = te[t] * te[t];
  __syncthreads();
  for (int o = 128; o > 0; o >>= 1){ if (t < o) red[t] += red[t + o]; __syncthreads(); }
  float nrm = sqrtf(red[0]);
  float inv = 1.f / fmaxf(nrm, 1e-12f);
  txt_n[b * C_ + t] = te[t] * inv;
}

// ---------- source (residual+LN) -> srcT bf16 [C][N], snb bf16 [N][C], cos ----------
__global__ __launch_bounds__(256) void k_source(
    const float* __restrict__ img, const float* __restrict__ attn_c,
    const float* __restrict__ ln_g, const float* __restrict__ ln_b,
    const float* __restrict__ txt_n,
    u16* __restrict__ srcT, u16* __restrict__ snb, float* __restrict__ cosv)
{
  int b = blockIdx.y;
  int n0 = blockIdx.x * TN;
  int t = threadIdx.x;
  __shared__ float x[C_][TN + 1];
  __shared__ float ps[8][TN];
  __shared__ float ps2[8][TN];
  __shared__ float ac_s[C_], g_s[C_], bb_s[C_], tn_s[C_];
  __shared__ float mean_s[TN], rstd_s[TN], rn_s[TN];
  ac_s[t] = attn_c[b * C_ + t];
  g_s[t]  = ln_g[t];
  bb_s[t] = ln_b[t];
  tn_s[t] = txt_n[b * C_ + t];
  const float* ib = img + (size_t)b * C_ * N_ + n0;
  for (int k = 0; k < TN; k++){
    int e = t + k * 256;
    int c = e >> 5, nn = e & 31;
    x[c][nn] = ib[(size_t)c * N_ + nn];
  }
  __syncthreads();
  for (int k = 0; k < TN; k++){
    int e = t + k * 256;
    int c = e >> 5, nn = e & 31;
    x[c][nn] += ac_s[c];
  }
  __syncthreads();
  {
    int p = t >> 5, nn = t & 31;
    float s1 = 0.f, s2 = 0.f;
    for (int j = 0; j < 32; j++){
      float v = x[p + 8 * j][nn];
      s1 += v; s2 += v * v;
    }
    ps[p][nn] = s1; ps2[p][nn] = s2;
  }
  __syncthreads();
  if (t < TN){
    float S1 = 0.f, S2 = 0.f;
    for (int pp = 0; pp < 8; pp++){ S1 += ps[pp][t]; S2 += ps2[pp][t]; }
    float mean = S1 * (1.f / C_);
    float var = S2 * (1.f / C_) - mean * mean;
    mean_s[t] = mean;
    rstd_s[t] = rsqrtf(var + 1e-5f);
  }
  __syncthreads();
  for (int k = 0; k < TN; k++){
    float sval = (x[t][k] - mean_s[k]) * rstd_s[k] * g_s[t] + bb_s[t];
    x[t][k] = sval;
  }
  for (int kq = 0; kq < TN; kq += 4){
    ushort4 pkv;
    pkv.x = f2bf(x[t][kq + 0]);
    pkv.y = f2bf(x[t][kq + 1]);
    pkv.z = f2bf(x[t][kq + 2]);
    pkv.w = f2bf(x[t][kq + 3]);
    *reinterpret_cast<ushort4*>(&srcT[(size_t)(b * C_ + t) * N_ + n0 + kq]) = pkv;
  }
  __syncthreads();
  {
    int p = t >> 5, nn = t & 31;
    float s2 = 0.f, sd = 0.f;
    for (int j = 0; j < 32; j++){
      int c = p + 8 * j;
      float v = x[c][nn];
      s2 += v * v; sd += v * tn_s[c];
    }
    ps[p][nn] = s2; ps2[p][nn] = sd;
  }
  __syncthreads();
  if (t < TN){
    float S2 = 0.f, SD = 0.f;
    for (int pp = 0; pp < 8; pp++){ S2 += ps[pp][t]; SD += ps2[pp][t]; }
    float nrm = sqrtf(S2);
    float rn = 1.f / fmaxf(nrm, 1e-12f);
    rn_s[t] = rn;
    cosv[(b << 12) + n0 + t] = SD * rn;
  }
  __syncthreads();
  for (int k = 0; k < TN; k++){
    snb[(size_t)((b << 12) + n0 + k) * C_ + t] = f2bf(x[t][k] * rn_s[k]);
  }
}

// ---------- marginals ----------
__global__ __launch_bounds__(256) void k_qmarg(const float* __restrict__ dens, float* __restrict__ q){
  int b = blockIdx.x, t = threadIdx.x;
  __shared__ float red[256];
  const float* d = dens + (size_t)b * N_;
  float s = 0.f;
  for (int n = t; n < N_; n += 256) s += fmaxf(d[n], 0.f) + 1e-6f;
  red[t] = s; __syncthreads();
  for (int o = 128; o > 0; o >>= 1){ if (t < o) red[t] += red[t + o]; __syncthreads(); }
  float inv = 1.f / red[0];
  for (int n = t; n < N_; n += 256) q[b * N_ + n] = (fmaxf(d[n], 0.f) + 1e-6f) * inv;
}

__global__ __launch_bounds__(256) void k_pmarg(const float* __restrict__ cosv,
    const float* __restrict__ temp_p, float* __restrict__ p){
  int b = blockIdx.x, t = threadIdx.x;
  __shared__ float red[256];
  float temp = fmaxf(temp_p[0], 0.01f);
  float inv_t = 1.f / temp;
  const float* cb = cosv + (size_t)b * N_;
  float m = -1e30f;
  for (int n = t; n < N_; n += 256) m = fmaxf(m, cb[n] * inv_t);
  red[t] = m; __syncthreads();
  for (int o = 128; o > 0; o >>= 1){ if (t < o) red[t] = fmaxf(red[t], red[t + o]); __syncthreads(); }
  m = red[0]; __syncthreads();
  float s = 0.f;
  for (int n = t; n < N_; n += 256) s += expf(cb[n] * inv_t - m);
  red[t] = s; __syncthreads();
  for (int o = 128; o > 0; o >>= 1){ if (t < o) red[t] += red[t + o]; __syncthreads(); }
  float invs = 1.f / red[0];
  for (int n = t; n < N_; n += 256) p[b * N_ + n] = expf(cb[n] * inv_t - m) * invs;
}

__global__ __launch_bounds__(256) void k_zero(float* __restrict__ p, int n){
  int i = blockIdx.x * 256 + threadIdx.x;
  if (i < n) p[i] = 0.f;
}

// ---------- K = exp(20*(sn sn^T - 1)) bf16 via MFMA, SYMMETRIC, two-pass epilogue ----------
// Upper-triangular tile grid; one 32 KB shbuf reused: Al|Bl -> Ct(direct) -> Ct(mirror).
__global__ __launch_bounds__(256) void k_kgen(
    const u16* __restrict__ snb, u16* __restrict__ Kp, float* __restrict__ colsum)
{
  int b = blockIdx.y;
  int kidx = blockIdx.x;
  int a = (int)((sqrtf(8.f * kidx + 1.f) - 1.f) * 0.5f);
  while ((a + 1) * (a + 2) / 2 <= kidx) a++;
  while (a * (a + 1) / 2 > kidx) a--;
  int bc = kidx - a * (a + 1) / 2;
  int n0 = a << 7, m0 = bc << 7;            // m0 <= n0
  bool diag = (m0 == n0);

  int t = threadIdx.x;
  int lane = t & 63, w = t >> 6;
  int wr = w >> 1, wc = w & 1;
  __shared__ __align__(16) u16 shbuf[128 * 128];    // 32 KB: Al|Bl, then Ct (twice)
  u16* Al = shbuf;
  u16* Bl = shbuf + 128 * 64;
  __shared__ float cs_col[128], cs_row[128];
  if (t < 128){ cs_col[t] = 0.f; cs_row[t] = 0.f; }
  f32x4 zero = {0.f, 0.f, 0.f, 0.f};
  f32x4 acc[4][4];
  #pragma unroll
  for (int i = 0; i < 4; i++){
    #pragma unroll
    for (int j = 0; j < 4; j++) acc[i][j] = zero;
  }
  const u16* sb = snb + (size_t)b * N_ * C_;
  const u16* ga = sb + (size_t)m0 * C_;
  const u16* gb = sb + (size_t)n0 * C_;
  const u16* Bsrc = diag ? Al : Bl;
  for (int kt = 0; kt < C_; kt += 64){
    stage_tile(ga + kt, C_, Al, t);
    if (!diag) stage_tile(gb + kt, C_, Bl, t);
    __syncthreads();
    #pragma unroll
    for (int kh = 0; kh < 2; kh++){
      short8 af[4], bfv[4];
      #pragma unroll
      for (int i = 0; i < 4; i++){
        af[i]  = frag_ld(Al,   wr * 64 + i * 16 + (lane & 15), kh * 4 + (lane >> 4));
        bfv[i] = frag_ld(Bsrc, wc * 64 + i * 16 + (lane & 15), kh * 4 + (lane >> 4));
      }
      #pragma unroll
      for (int i = 0; i < 4; i++){
        #pragma unroll
        for (int j = 0; j < 4; j++)
          acc[i][j] = MFMA_BF16(af[i], bfv[j], acc[i][j]);
      }
    }
    __syncthreads();
  }
  u16* Ct = shbuf;
  u16* Kb = Kp + (size_t)b * N_ * N_;
  // ---- pass 1: direct tile (rows m, cols n) ----
  float rsum[16];
  #pragma unroll
  for (int q = 0; q < 16; q++) rsum[q] = 0.f;
  #pragma unroll
  for (int j = 0; j < 4; j++){
    int col = wc * 64 + j * 16 + (lane & 15);
    float csum = 0.f;
    #pragma unroll
    for (int i = 0; i < 4; i++){
      int rb = wr * 64 + i * 16 + (lane >> 4) * 4;
      #pragma unroll
      for (int r = 0; r < 4; r++){
        float e = expf(20.f * (acc[i][j][r] - 1.f));
        u16 pk = f2bf(e);
        float ev = bf2f(pk);
        csum += ev;
        rsum[i * 4 + r] += ev;
        int row = rb + r;
        Ct[row * 128 + ((((col >> 3) ^ (row & 7)) << 3) | (col & 7))] = pk;
      }
    }
    atomicAdd(&cs_col[col], csum);
  }
  if (!diag){
    #pragma unroll
    for (int q = 0; q < 16; q++){
      float v = rsum[q];
      v += __shfl_xor(v, 1); v += __shfl_xor(v, 2);
      v += __shfl_xor(v, 4); v += __shfl_xor(v, 8);
      if ((lane & 15) == 0){
        int row = wr * 64 + (q >> 2) * 16 + (lane >> 4) * 4 + (q & 3);
        atomicAdd(&cs_row[row], v);
      }
    }
  }
  __syncthreads();
  for (int e = t; e < 2048; e += 256){
    int row = e >> 4, un = e & 15;
    short8 v8 = *(const short8*)(Ct + row * 128 + ((un ^ (row & 7)) << 3));
    *reinterpret_cast<short8*>(&Kb[(size_t)(m0 + row) * N_ + n0 + (un << 3)]) = v8;
  }
  // ---- pass 2: mirror tile (rows n-col, cols m-row), recompute exp from live acc ----
  if (!diag){
    __syncthreads();
    #pragma unroll
    for (int j = 0; j < 4; j++){
      int col = wc * 64 + j * 16 + (lane & 15);
      #pragma unroll
      for (int i = 0; i < 4; i++){
        int rb = wr * 64 + i * 16 + (lane >> 4) * 4;
        #pragma unroll
        for (int r = 0; r < 4; r++){
          float e = expf(20.f * (acc[i][j][r] - 1.f));
          int rowm = rb + r;
          Ct[col * 128 + ((((rowm >> 3) ^ (col & 7)) << 3) | (rowm & 7))] = f2bf(e);
        }
      }
    }
    __syncthreads();
    for (int e = t; e < 2048; e += 256){
      int c = e >> 4, un = e & 15;
      short8 v8 = *(const short8*)(Ct + c * 128 + ((un ^ (c & 7)) << 3));
      *reinterpret_cast<short8*>(&Kb[(size_t)(n0 + c) * N_ + m0 + (un << 3)]) = v8;
    }
  }
  if (t < 128){
    atomicAdd(&colsum[b * N_ + n0 + t], cs_col[t]);
    if (!diag) atomicAdd(&colsum[b * N_ + m0 + t], cs_row[t]);
  }
}

__global__ __launch_bounds__(256) void k_div(
    const float* __restrict__ marg, const float* __restrict__ denom, float* __restrict__ outp){
  int i = blockIdx.x * 256 + threadIdx.x;
  if (i < B_ * N_) outp[i] = marg[i] / (denom[i] + 1e-8f);
}

// ---------- out[r] = marg[r] / (K_row_r . x + 1e-8)  (K symmetric), 8 rows/block ----------
__global__ __launch_bounds__(256) void k_mv(
    const u16* __restrict__ Kp, const float* __restrict__ x,
    const float* __restrict__ marg, float* __restrict__ outp)
{
  int r0 = blockIdx.x * 8;
  int b = r0 >> 12;
  int t = threadIdx.x, w = t >> 6, lane = t & 63;
  __shared__ __align__(16) float xs[N_];
  const float* xb = x + b * N_;
  for (int i = t; i < N_ / 4; i += 256)
    reinterpret_cast<float4*>(xs)[i] = reinterpret_cast<const float4*>(xb)[i];
  __syncthreads();
  int r = r0 + w * 2;
  const u16* Kr0 = Kp + (size_t)b * N_ * N_ + (size_t)(r & (N_ - 1)) * N_;
  const u16* Kr1 = Kr0 + N_;
  float acc0 = 0.f, acc1 = 0.f;
  #pragma unroll
  for (int p = 0; p < 8; p++){
    int idx = p * 512 + lane * 8;
    short8 k0 = *reinterpret_cast<const short8*>(Kr0 + idx);
    short8 k1 = *reinterpret_cast<const short8*>(Kr1 + idx);
    float4 x0 = *reinterpret_cast<const float4*>(xs + idx);
    float4 x1 = *reinterpret_cast<const float4*>(xs + idx + 4);
    acc0 += bf2f((u16)k0[0]) * x0.x + bf2f((u16)k0[1]) * x0.y
          + bf2f((u16)k0[2]) * x0.z + bf2f((u16)k0[3]) * x0.w
          + bf2f((u16)k0[4]) * x1.x + bf2f((u16)k0[5]) * x1.y
          + bf2f((u16)k0[6]) * x1.z + bf2f((u16)k0[7]) * x1.w;
    acc1 += bf2f((u16)k1[0]) * x0.x + bf2f((u16)k1[1]) * x0.y
          + bf2f((u16)k1[2]) * x0.z + bf2f((u16)k1[3]) * x0.w
          + bf2f((u16)k1[4]) * x1.x + bf2f((u16)k1[5]) * x1.y
          + bf2f((u16)k1[6]) * x1.z + bf2f((u16)k1[7]) * x1.w;
  }
  for (int o = 32; o > 0; o >>= 1){
    acc0 += __shfl_down(acc0, o);
    acc1 += __shfl_down(acc1, o);
  }
  if (lane == 0){
    outp[r] = marg[r] / (acc0 + 1e-8f);
    outp[r + 1] = marg[r + 1] / (acc1 + 1e-8f);
  }
}

// ---------- usrcT[c][n] = srcT[c][n] * u[n] ----------
__global__ __launch_bounds__(256) void k_uscale(
    const u16* __restrict__ srcT, const float* __restrict__ uu, u16* __restrict__ usrcT)
{
  int i = blockIdx.x * 256 + threadIdx.x;
  int n8 = i & (N_ / 8 - 1);
  int row = i >> 9;
  int b = row >> 8;
  const u16* s = srcT + (size_t)row * N_ + n8 * 8;
  short8 v = *reinterpret_cast<const short8*>(s);
  const float* ub = uu + b * N_ + n8 * 8;
  short8 o;
  #pragma unroll
  for (int q = 0; q < 8; q++) o[q] = (short)f2bf(bf2f((u16)v[q]) * ub[q]);
  *reinterpret_cast<short8*>(usrcT + (size_t)row * N_ + n8 * 8) = o;
}

// ---------- part[ks][m][c] = vv[m] * sum_{n in ks chunk} K[m][n]*usrc[n][c] ----------
// 512 threads, tile 128m x 256c (full C in-block -> K read ONCE), bf16 out via 2-half restage.
__global__ __launch_bounds__(512) void k_full(
    const u16* __restrict__ Kp, const u16* __restrict__ usrcT,
    const float* __restrict__ vvv,
    u16* __restrict__ p0, u16* __restrict__ p1,
    u16* __restrict__ p2, u16* __restrict__ p3)
{
  int m0 = blockIdx.x << 7;
  int b = blockIdx.z >> 2, ks = blockIdx.z & 3;
  int t = threadIdx.x, lane = t & 63, w = t >> 6;
  int wr = w >> 2, wc = w & 3;              // 2 x 4 wave grid: 64m x 64c each
  __shared__ __align__(16) u16 shbuf[128 * 64 + 256 * 64];  // Al (16KB) | Bl (32KB)
  __shared__ float vsm[128];
  u16* Al = shbuf;
  u16* Bl = shbuf + 128 * 64;
  if (t < 128) vsm[t] = vvv[b * N_ + m0 + t];
  f32x4 zero = {0.f, 0.f, 0.f, 0.f};
  f32x4 acc[4][4];
  #pragma unroll
  for (int i = 0; i < 4; i++){
    #pragma unroll
    for (int j = 0; j < 4; j++) acc[i][j] = zero;
  }
  const u16* ka = Kp + (size_t)b * N_ * N_ + (size_t)m0 * N_ + ks * (N_ / KSPLIT);
  const u16* ub = usrcT + (size_t)b * C_ * N_ + ks * (N_ / KSPLIT);
  for (int kt = 0; kt < N_ / KSPLIT; kt += 64){
    stage_tile512_128(ka + kt, N_, Al, t);
    stage_tile512_256(ub + kt, N_, Bl, t);
    __syncthreads();
    #pragma unroll
    for (int kh = 0; kh < 2; kh++){
      short8 af[4], bfv[4];
      #pragma unroll
      for (int i = 0; i < 4; i++){
        af[i]  = frag_ld(Al, wr * 64 + i * 16 + (lane & 15), kh * 4 + (lane >> 4));
        bfv[i] = frag_ld(Bl, wc * 64 + i * 16 + (lane & 15), kh * 4 + (lane >> 4));
      }
      #pragma unroll
      for (int i = 0; i < 4; i++){
        #pragma unroll
        for (int j = 0; j < 4; j++)
          acc[i][j] = MFMA_BF16(af[i], bfv[j], acc[i][j]);
      }
    }
    __syncthreads();
  }
  // two-half restage (Ct = 128x128 bf16 = 32 KB over shbuf) -> coalesced stores
  u16* Ct = shbuf;
  u16* P = (ks == 0) ? p0 : (ks == 1) ? p1 : (ks == 2) ? p2 : p3;
  #pragma unroll
  for (int ch = 0; ch < 2; ch++){
    __syncthreads();
    if ((wc >> 1) == ch){
      #pragma unroll
      for (int j = 0; j < 4; j++){
        int colh = (wc & 1) * 64 + j * 16 + (lane & 15);
        #pragma unroll
        for (int i = 0; i < 4; i++){
          int rb = wr * 64 + i * 16 + (lane >> 4) * 4;
          #pragma unroll
          for (int r = 0; r < 4; r++){
            int row = rb + r;
            Ct[row * 128 + ((((colh >> 3) ^ (row & 7)) << 3) | (colh & 7))] =
                f2bf(acc[i][j][r] * vsm[row]);
          }
        }
      }
    }
    __syncthreads();
    for (int e = t; e < 2048; e += 512){
      int row = e >> 4, un = e & 15;
      short8 v8 = *(const short8*)(Ct + row * 128 + ((un ^ (row & 7)) << 3));
      *reinterpret_cast<short8*>(&P[(size_t)((b << 12) + m0 + row) * C_ + ch * 128 + (un << 3)]) = v8;
    }
  }
}

// ---------- cast opw (f32 256x256) to bf16 ----------
__global__ __launch_bounds__(256) void k_wcast(const float* __restrict__ w, u16* __restrict__ o){
  int i = blockIdx.x * 256 + threadIdx.x;
  o[i] = f2bf(w[i]);
}

// ---------- out_feat = img + 1x1conv(p0+p1+p2+p3) via MFMA (partials pre-scaled by vv) ----------
__global__ __launch_bounds__(256) void k_opconv(
    const u16* __restrict__ opwB, const float* __restrict__ opb,
    const u16* __restrict__ p0, const u16* __restrict__ p1,
    const u16* __restrict__ p2, const u16* __restrict__ p3,
    const float* __restrict__ img, float* __restrict__ outf)
{
  int b = blockIdx.z;
  int n0 = blockIdx.x << 7;
  int co0 = blockIdx.y << 7;
  int t = threadIdx.x, lane = t & 63, w = t >> 6;
  int wr = w >> 1, wc = w & 1;
  __shared__ __align__(16) u16 Al[128 * 64];   // opw rows=co
  __shared__ __align__(16) u16 Bl[128 * 64];   // fused rows=n
  f32x4 zero = {0.f, 0.f, 0.f, 0.f};
  f32x4 acc[4][4];
  #pragma unroll
  for (int i = 0; i < 4; i++){
    #pragma unroll
    for (int j = 0; j < 4; j++) acc[i][j] = zero;
  }
  for (int ct = 0; ct < C_; ct += 64){
    stage_tile(opwB + (size_t)co0 * C_ + ct, C_, Al, t);
    // reg-stage B: sum 4 bf16 partials, write swizzled content to linear LDS
    #pragma unroll
    for (int q = 0; q < 4; q++){
      int e = q * 256 + t;
      int row = e >> 3, slot = e & 7;
      int col = ct + ((slot ^ (row & 7)) << 3);
      size_t idx = (size_t)((b << 12) + n0 + row) * C_ + col;
      short8 a0 = *reinterpret_cast<const short8*>(p0 + idx);
      short8 a1 = *reinterpret_cast<const short8*>(p1 + idx);
      short8 a2 = *reinterpret_cast<const short8*>(p2 + idx);
      short8 a3 = *reinterpret_cast<const short8*>(p3 + idx);
      short8 o;
      #pragma unroll
      for (int k = 0; k < 8; k++)
        o[k] = (short)f2bf(bf2f((u16)a0[k]) + bf2f((u16)a1[k]) + bf2f((u16)a2[k]) + bf2f((u16)a3[k]));
      *reinterpret_cast<short8*>(Bl + (size_t)e * 8) = o;
    }
    __syncthreads();
    #pragma unroll
    for (int kh = 0; kh < 2; kh++){
      short8 af[4], bfv[4];
      #pragma unroll
      for (int i = 0; i < 4; i++){
        af[i]  = frag_ld(Al, wr * 64 + i * 16 + (lane & 15), kh * 4 + (lane >> 4));
        bfv[i] = frag_ld(Bl, wc * 64 + i * 16 + (lane & 15), kh * 4 + (lane >> 4));
      }
      #pragma unroll
      for (int i = 0; i < 4; i++){
        #pragma unroll
        for (int j = 0; j < 4; j++)
          acc[i][j] = MFMA_BF16(af[i], bfv[j], acc[i][j]);
      }
    }
    __syncthreads();
  }
  #pragma unroll
  for (int i = 0; i < 4; i++){
    int cb = co0 + wr * 64 + i * 16 + (lane >> 4) * 4;
    #pragma unroll
    for (int j = 0; j < 4; j++){
      int nc = n0 + wc * 64 + j * 16 + (lane & 15);
      #pragma unroll
      for (int r = 0; r < 4; r++){
        int co = cb + r;
        size_t oi = (size_t)(b * C_ + co) * N_ + nc;
        outf[oi] = acc[i][j][r] + img[oi] + opb[co];
      }
    }
  }
}

// ---------- transpose out_feat -> padded bf16 [b][px'][ci] ----------
__global__ __launch_bounds__(256) void k_tr(const float* __restrict__ outf, u16* __restrict__ inTp)
{
  int b = blockIdx.z;
  int c0 = blockIdx.y << 6;
  int px0 = blockIdx.x << 6;
  int t = threadIdx.x;
  __shared__ float tile[64][65];
  int tx = t & 63, ty4 = t >> 6;
  for (int cc = ty4; cc < 64; cc += 4)
    tile[cc][tx] = outf[((size_t)(b * C_) + c0 + cc) * N_ + px0 + tx];
  __syncthreads();
  int p = t >> 2, cg = (t & 3) << 4;
  int px = px0 + p;
  int y = px >> 6, x = px & 63;
  int pxp = y * 66 + x + 1;
  u16* dst = inTp + ((size_t)b * PXTOT + PXPAD + pxp) * C_ + c0 + cg;
  #pragma unroll
  for (int q = 0; q < 16; q += 4){
    ushort4 pk;
    pk.x = f2bf(tile[cg + q + 0][p]);
    pk.y = f2bf(tile[cg + q + 1][p]);
    pk.z = f2bf(tile[cg + q + 2][p]);
    pk.w = f2bf(tile[cg + q + 3][p]);
    *reinterpret_cast<ushort4*>(dst + q) = pk;
  }
}

// ---------- weights -> Wt[tap][co(256 fused)][ci] bf16, fused bias ----------
__global__ __launch_bounds__(256) void k_wtr(
    const float* __restrict__ hm1_w, const float* __restrict__ hv1_w,
    const float* __restrict__ hm1_b, const float* __restrict__ hv1_b,
    u16* __restrict__ Wt, float* __restrict__ biasF)
{
  int i = blockIdx.x * 256 + threadIdx.x;   // < 9*256*256
  int ci = i & 255, co = (i >> 8) & 255, tap = i >> 16;
  float v = (co < CH_) ? hm1_w[((size_t)co * C_ + ci) * 9 + tap]
                       : hv1_w[((size_t)(co - CH_) * C_ + ci) * 9 + tap];
  Wt[i] = f2bf(v);
  if (i < CH_) biasF[i] = hm1_b[i];
  else if (i < 2 * CH_) biasF[i] = hv1_b[i - CH_];
}

// ---------- fused 3x3 conv (both heads) as implicit GEMM: C[co][px'] (bf16 out) ----------
__global__ __launch_bounds__(256) void k_conv3m(
    const u16* __restrict__ inTp, const u16* __restrict__ Wt,
    const float* __restrict__ biasF,
    u16* __restrict__ q0, u16* __restrict__ q1,
    u16* __restrict__ q2, u16* __restrict__ q3)
{
  int px0 = blockIdx.x << 7;           // 0..32 (33 tiles of 128 px')
  int cot = blockIdx.y;                // 0..1 (co halves of 256 fused)
  int b = blockIdx.z >> 2, ks = blockIdx.z & 3;
  int t = threadIdx.x, lane = t & 63, w = t >> 6;
  int wr = w >> 1, wc = w & 1;
  __shared__ __align__(16) u16 Al[128 * 64];   // weights: 128 co rows x 64 ci
  __shared__ __align__(16) u16 Bl[128 * 64];   // input:   128 px rows x 64 ci
  f32x4 zero = {0.f, 0.f, 0.f, 0.f};
  f32x4 acc[4][4];
  #pragma unroll
  for (int i = 0; i < 4; i++){
    #pragma unroll
    for (int j = 0; j < 4; j++) acc[i][j] = zero;
  }
  const u16* inb = inTp + ((size_t)b * PXTOT + PXPAD + px0) * C_;
  for (int s = ks * 9; s < ks * 9 + 9; s++){
    int tap = s >> 2, cic = (s & 3) << 6;
    int ky = tap / 3, kx = tap - ky * 3;
    int off = (ky - 1) * 66 + (kx - 1);
    stage_tile(Wt + ((size_t)tap * 256 + cot * 128) * C_ + cic, C_, Al, t);
    stage_tile(inb + (ptrdiff_t)off * C_ + cic, C_, Bl, t);
    __syncthreads();
    #pragma unroll
    for (int kh = 0; kh < 2; kh++){
      short8 af[4], bfv[4];
      #pragma unroll
      for (int i = 0; i < 4; i++){
        af[i]  = frag_ld(Al, wr * 64 + i * 16 + (lane & 15), kh * 4 + (lane >> 4));
        bfv[i] = frag_ld(Bl, wc * 64 + i * 16 + (lane & 15), kh * 4 + (lane >> 4));
      }
      #pragma unroll
      for (int i = 0; i < 4; i++){
        #pragma unroll
        for (int j = 0; j < 4; j++)
          acc[i][j] = MFMA_BF16(af[i], bfv[j], acc[i][j]);
      }
    }
    __syncthreads();
  }
  u16* P = (ks == 0) ? q0 : (ks == 1) ? q1 : (ks == 2) ? q2 : q3;
  #pragma unroll
  for (int i = 0; i < 4; i++){
    #pragma unroll
    for (int j = 0; j < 4; j++){
      int pxp = px0 + wc * 64 + j * 16 + (lane & 15);
      int y = pxp / 66;
      int xm = pxp - y * 66;
      bool valid = (xm >= 1 && xm <= 64);
      int outn = y * 64 + xm - 1;
      #pragma unroll
      for (int r = 0; r < 4; r++){
        int co = cot * 128 + wr * 64 + i * 16 + (lane >> 4) * 4 + r;
        if (valid){
          float bco = (ks == 0) ? biasF[co] : 0.f;
          P[((size_t)(b * 256 + co)) * N_ + outn] = f2bf(acc[i][j][r] + bco);
        }
      }
    }
  }
}

// ---------- batchnorm stats over (B,H,W) per fused channel (sums 4 K-parts) ----------
__global__ __launch_bounds__(256) void k_bnstats2(
    const u16* __restrict__ p0, const u16* __restrict__ p1,
    const u16* __restrict__ p2, const u16* __restrict__ p3,
    float* __restrict__ stats)
{
  int ch = blockIdx.x, t = threadIdx.x;   // ch in [0,256)
  __shared__ float r1[256], r2[256];
  float s1 = 0.f, s2 = 0.f;
  for (int i = t; i < B_ * N_; i += 256){
    int b = i >> 12, n = i & (N_ - 1);
    size_t idx = ((size_t)(b * 256 + ch)) * N_ + n;
    float v = bf2f(p0[idx]) + bf2f(p1[idx]) + bf2f(p2[idx]) + bf2f(p3[idx]);
    s1 += v; s2 += v * v;
  }
  r1[t] = s1; r2[t] = s2; __syncthreads();
  for (int o = 128; o > 0; o >>= 1){
    if (t < o){ r1[t] += r1[t + o]; r2[t] += r2[t + o]; }
    __syncthreads();
  }
  if (t == 0){
    float mean = r1[0] / (float)(B_ * N_);
    float var = r2[0] / (float)(B_ * N_) - mean * mean;
    stats[ch * 2] = mean;
    stats[ch * 2 + 1] = rsqrtf(var + 1e-5f);
  }
}

// ---------- relu(bn(mid)) -> 1x1 conv to 2 channels (per head, choff) ----------
__global__ __launch_bounds__(256) void k_head2(
    const u16* __restrict__ p0, const u16* __restrict__ p1,
    const u16* __restrict__ p2, const u16* __restrict__ p3,
    const float* __restrict__ stats,
    const float* __restrict__ g, const float* __restrict__ bb,
    const float* __restrict__ w2, const float* __restrict__ b2,
    float* __restrict__ outp, int choff)
{
  int idx = blockIdx.x * 256 + threadIdx.x;
  int b = idx >> 12, n = idx & (N_ - 1);
  float a0 = 0.f, a1 = 0.f;
  for (int ch = 0; ch < CH_; ch++){
    int fc = choff + ch;
    size_t id = ((size_t)(b * 256 + fc)) * N_ + n;
    float v = bf2f(p0[id]) + bf2f(p1[id]) + bf2f(p2[id]) + bf2f(p3[id]);
    float rr = (v - stats[fc * 2]) * stats[fc * 2 + 1] * g[ch] + bb[ch];
    rr = fmaxf(rr, 0.f);
    a0 += w2[ch] * rr;
    a1 += w2[CH_ + ch] * rr;
  }
  outp[(size_t)(b * 2) * N_ + n] = a0 + b2[0];
  outp[(size_t)(b * 2 + 1) * N_ + n] = a1 + b2[1];
}

extern "C" void kernel_launch(void* const* d_in, const int* in_sizes, int n_in,
                              void* d_out, int out_size, void* d_ws, size_t ws_size,
                              hipStream_t stream)
{
  const float* img   = (const float*)d_in[0];
  const float* txt   = (const float*)d_in[1];
  const float* dens  = (const float*)d_in[2];
  const float* tp_w  = (const float*)d_in[3];
  const float* tp_b  = (const float*)d_in[4];
  const float* wv    = (const float*)d_in[9];
  const float* bv    = (const float*)d_in[10];
  const float* wo    = (const float*)d_in[11];
  const float* bo    = (const float*)d_in[12];
  const float* ln_g  = (const float*)d_in[13];
  const float* ln_b  = (const float*)d_in[14];
  const float* op_w  = (const float*)d_in[15];
  const float* op_b  = (const float*)d_in[16];
  const float* hm1_w = (const float*)d_in[17];
  const float* hm1_b = (const float*)d_in[18];
  const float* hm_g  = (const float*)d_in[19];
  const float* hm_b  = (const float*)d_in[20];
  const float* hm2_w = (const float*)d_in[21];
  const float* hm2_b = (const float*)d_in[22];
  const float* hv1_w = (const float*)d_in[23];
  const float* hv1_b = (const float*)d_in[24];
  const float* hv_g  = (const float*)d_in[25];
  const float* hv_b  = (const float*)d_in[26];
  const float* hv2_w = (const float*)d_in[27];
  const float* hv2_b = (const float*)d_in[28];
  const float* temp  = (const float*)d_in[29];

  char* wsb = (char*)d_ws;
  size_t off = 0;
  auto alloc = [&](size_t bytes) -> void* {
    void* p = wsb + off;
    off += (bytes + 255) & ~(size_t)255;
    return p;
  };
  u16*   Km     = (u16*)  alloc((size_t)B_ * N_ * N_ * sizeof(u16));   // 67.1 MB
  u16*   snb16  = (u16*)  alloc((size_t)B_ * N_ * C_ * sizeof(u16));   // 4.19 MB (part0 alias)
  u16*   srcT16 = (u16*)  alloc((size_t)B_ * C_ * N_ * sizeof(u16));   // 4.19 MB
  u16*   usrcT  = (u16*)  alloc((size_t)B_ * C_ * N_ * sizeof(u16));   // 4.19 MB
  u16*   part1  = (u16*)  alloc((size_t)B_ * N_ * C_ * sizeof(u16));   // 4.19 MB
  u16*   part2  = (u16*)  alloc((size_t)B_ * N_ * C_ * sizeof(u16));   // 4.19 MB
  u16*   part3  = (u16*)  alloc((size_t)B_ * N_ * C_ * sizeof(u16));   // 4.19 MB
  u16*   inTp   = (u16*)  alloc((size_t)B_ * PXTOT * C_ * sizeof(u16));// 4.52 MB
  u16*   Wt     = (u16*)  alloc((size_t)9 * 256 * C_ * sizeof(u16));   // 1.18 MB
  u16*   opwB   = (u16*)  alloc((size_t)C_ * C_ * sizeof(u16));        // 131 KB
  float* biasF  = (float*)alloc(256 * sizeof(float));
  float* txt_emb= (float*)alloc(B_ * C_ * sizeof(float));
  float* attn_c = (float*)alloc(B_ * C_ * sizeof(float));
  float* txt_n  = (float*)alloc(B_ * C_ * sizeof(float));
  float* cosv   = (float*)alloc(B_ * N_ * sizeof(float));
  float* qm     = (float*)alloc(B_ * N_ * sizeof(float));
  float* pm     = (float*)alloc(B_ * N_ * sizeof(float));
  float* uu     = (float*)alloc(B_ * N_ * sizeof(float));
  float* vvv    = (float*)alloc(B_ * N_ * sizeof(float));
  float* colsum = (float*)alloc(B_ * N_ * sizeof(float));
  float* stats  = (float*)alloc(256 * 2 * sizeof(float));

  // alias: part0 over snb16 (snb dead after kgen; part0 written by k_full)
  u16* part0 = snb16;

  float* outf  = (float*)d_out;
  float* outhm = outf + (size_t)B_ * C_ * N_;
  float* outhv = outhm + (size_t)B_ * 2 * N_;

  k_text<<<B_, 256, 0, stream>>>(txt, tp_w, tp_b, wv, bv, wo, bo, txt_emb, attn_c, txt_n);
  k_source<<<dim3(N_ / TN, B_), 256, 0, stream>>>(img, attn_c, ln_g, ln_b, txt_n, srcT16, snb16, cosv);
  k_qmarg<<<B_, 256, 0, stream>>>(dens, qm);
  k_pmarg<<<B_, 256, 0, stream>>>(cosv, temp, pm);
  k_zero<<<(B_ * N_ + 255) / 256, 256, 0, stream>>>(colsum, B_ * N_);
  // conv/opconv prep with no deps on GEMM chain
  k_wtr<<<9 * 256, 256, 0, stream>>>(hm1_w, hv1_w, hm1_b, hv1_b, Wt, biasF);
  k_wcast<<<C_ * C_ / 256, 256, 0, stream>>>(op_w, opwB);
  k_zero<<<((int)((size_t)B_ * PXTOT * C_ / 2) + 255) / 256, 256, 0, stream>>>((float*)inTp, (int)((size_t)B_ * PXTOT * C_ / 2));
  // symmetric K generation: 528 upper-triangular tile pairs per batch
  k_kgen<<<dim3(528, B_), 256, 0, stream>>>(snb16, Km, colsum);
  // Sinkhorn (K symmetric: K^T x == K x)
  k_div<<<(B_ * N_ + 255) / 256, 256, 0, stream>>>(qm, colsum, vvv);        // vv1
  k_mv<<<B_ * N_ / 8, 256, 0, stream>>>(Km, vvv, pm, uu);                   // u1
  k_mv<<<B_ * N_ / 8, 256, 0, stream>>>(Km, uu, qm, vvv);                   // vv2
  k_mv<<<B_ * N_ / 8, 256, 0, stream>>>(Km, vvv, pm, uu);                   // u2
  k_mv<<<B_ * N_ / 8, 256, 0, stream>>>(Km, uu, qm, vvv);                   // vv3
  k_mv<<<B_ * N_ / 8, 256, 0, stream>>>(Km, vvv, pm, uu);                   // u3
  k_uscale<<<(B_ * C_ * N_ / 8 + 255) / 256, 256, 0, stream>>>(srcT16, uu, usrcT);
  k_full<<<dim3(N_ / 128, 1, B_ * KSPLIT), 512, 0, stream>>>(Km, usrcT, vvv, part0, part1, part2, part3);
  k_opconv<<<dim3(N_ / 128, C_ / 128, B_), 256, 0, stream>>>(opwB, op_b, part0, part1, part2, part3, img, outf);
  // fused heads: transpose -> implicit-GEMM conv (both heads) -> BN stats -> heads
  k_tr<<<dim3(N_ / 64, 4, B_), 256, 0, stream>>>(outf, inTp);
  k_conv3m<<<dim3(33, 2, B_ * KSPLIT), 256, 0, stream>>>(inTp, Wt, biasF, part0, part1, part2, part3);
  k_bnstats2<<<256, 256, 0, stream>>>(part0, part1, part2, part3, stats);
  k_head2<<<B_ * N_ / 256, 256, 0, stream>>>(part0, part1, part2, part3, stats, hm_g, hm_b, hm2_w, hm2_b, outhm, 0);
  k_head2<<<B_ * N_ / 256, 256, 0, stream>>>(part0, part1, part2, part3, stats, hv_g, hv_b, hv2_w, hv2_b, outhv, CH_);
}

// Round 7
// 278.794 us; speedup vs baseline: 1.2493x; 1.2312x over previous
//
#include <hip/hip_runtime.h>
#include <math.h>

#define B_ 2
#define C_ 256
#define N_ 4096
#define TXT_ 512
#define CH_ 128
#define TN 32
#define KSPLIT 4
#define PXR 4224          // 64 * 66 padded-pixel rows per batch
#define PXPAD 96          // halo pad rows each side
#define PXTOT (PXR + 2 * PXPAD)

typedef unsigned short u16;
typedef __attribute__((ext_vector_type(8))) short short8;
typedef __attribute__((ext_vector_type(4))) float f32x4;

__device__ __forceinline__ float bf2f(u16 v){
  union { unsigned u; float f; } w; w.u = ((unsigned)v) << 16; return w.f;
}
__device__ __forceinline__ u16 f2bf(float f){
  union { float f; unsigned u; } w; w.f = f;
  unsigned r = w.u + 0x7fffu + ((w.u >> 16) & 1u);
  return (u16)(r >> 16);
}

#define MFMA_BF16(a,b,c) __builtin_amdgcn_mfma_f32_16x16x32_bf16(a,b,c,0,0,0)

// Stage a 128-row x 64-col bf16 tile (256 threads). Pre-swizzled source, linear LDS dest.
__device__ __forceinline__ void stage_tile(const u16* __restrict__ g, int stride, u16* lds, int t)
{
  #pragma unroll
  for (int q = 0; q < 4; q++){
    int e = q * 256 + t;          // 16B unit index
    int row = e >> 3;
    int slot = e & 7;
    const u16* gp = g + (size_t)row * stride + ((slot ^ (row & 7)) << 3);
    u16* lp = lds + (size_t)e * 8;
    __builtin_amdgcn_global_load_lds((const __attribute__((address_space(1))) void*)gp,
                                     (__attribute__((address_space(3))) void*)lp, 16, 0, 0);
  }
}

// 512-thread variants: 64 rows and 256 rows.
__device__ __forceinline__ void stage_tile512_64(const u16* __restrict__ g, int stride, u16* lds, int t)
{
  int e = t;                      // 512 units = 64 rows x 8 slots
  int row = e >> 3;
  int slot = e & 7;
  const u16* gp = g + (size_t)row * stride + ((slot ^ (row & 7)) << 3);
  u16* lp = lds + (size_t)e * 8;
  __builtin_amdgcn_global_load_lds((const __attribute__((address_space(1))) void*)gp,
                                   (__attribute__((address_space(3))) void*)lp, 16, 0, 0);
}
__device__ __forceinline__ void stage_tile512_256(const u16* __restrict__ g, int stride, u16* lds, int t)
{
  #pragma unroll
  for (int q = 0; q < 4; q++){
    int e = q * 512 + t;          // 2048 units
    int row = e >> 3;
    int slot = e & 7;
    const u16* gp = g + (size_t)row * stride + ((slot ^ (row & 7)) << 3);
    u16* lp = lds + (size_t)e * 8;
    __builtin_amdgcn_global_load_lds((const __attribute__((address_space(1))) void*)gp,
                                     (__attribute__((address_space(3))) void*)lp, 16, 0, 0);
  }
}

__device__ __forceinline__ short8 frag_ld(const u16* lds, int row, int slot)
{
  return *(const short8*)(lds + row * 64 + ((slot ^ (row & 7)) << 3));
}

// ---------- text pipeline: txt_emb, attn constant (v@wo^T+bo), txt_n ----------
__global__ __launch_bounds__(256) void k_text(
    const float* __restrict__ txt, const float* __restrict__ tpw,
    const float* __restrict__ tpb, const float* __restrict__ wv,
    const float* __restrict__ bv, const float* __restrict__ wo,
    const float* __restrict__ bo,
    float* __restrict__ txt_emb, float* __restrict__ attn_c, float* __restrict__ txt_n)
{
  int b = blockIdx.x, t = threadIdx.x;
  __shared__ float te[C_], vs[C_], red[C_];
  const float* tb = txt + b * TXT_;
  const float* wr = tpw + (size_t)t * TXT_;
  float s = 0.f;
  for (int j = 0; j < TXT_; j++) s += tb[j] * wr[j];
  s += tpb[t];
  te[t] = s;
  txt_emb[b * C_ + t] = s;
  __syncthreads();
  float sv = 0.f;
  const float* wvr = wv + (size_t)t * C_;
  for (int j = 0; j < C_; j++) sv += te[j] * wvr[j];
  sv += bv[t];
  vs[t] = sv;
  __syncthreads();
  float sa = 0.f;
  const float* wor = wo + (size_t)t * C_;
  for (int j = 0; j < C_; j++) sa += vs[j] * wor[j];
  sa += bo[t];
  attn_c[b * C_ + t] = sa;
  red[t] = te[t] * te[t];
  __syncthreads();
  for (int o = 128; o > 0; o >>= 1){ if (t < o) red[t] += red[t + o]; __syncthreads(); }
  float nrm = sqrtf(red[0]);
  float inv = 1.f / fmaxf(nrm, 1e-12f);
  txt_n[b * C_ + t] = te[t] * inv;
}

// ---------- source (residual+LN) -> srcT bf16 [C][N], snb bf16 [N][C], cos ----------
__global__ __launch_bounds__(256) void k_source(
    const float* __restrict__ img, const float* __restrict__ attn_c,
    const float* __restrict__ ln_g, const float* __restrict__ ln_b,
    const float* __restrict__ txt_n,
    u16* __restrict__ srcT, u16* __restrict__ snb, float* __restrict__ cosv)
{
  int b = blockIdx.y;
  int n0 = blockIdx.x * TN;
  int t = threadIdx.x;
  __shared__ float x[C_][TN + 1];
  __shared__ float ps[8][TN];
  __shared__ float ps2[8][TN];
  __shared__ float ac_s[C_], g_s[C_], bb_s[C_], tn_s[C_];
  __shared__ float mean_s[TN], rstd_s[TN], rn_s[TN];
  ac_s[t] = attn_c[b * C_ + t];
  g_s[t]  = ln_g[t];
  bb_s[t] = ln_b[t];
  tn_s[t] = txt_n[b * C_ + t];
  const float* ib = img + (size_t)b * C_ * N_ + n0;
  for (int k = 0; k < TN; k++){
    int e = t + k * 256;
    int c = e >> 5, nn = e & 31;
    x[c][nn] = ib[(size_t)c * N_ + nn];
  }
  __syncthreads();
  for (int k = 0; k < TN; k++){
    int e = t + k * 256;
    int c = e >> 5, nn = e & 31;
    x[c][nn] += ac_s[c];
  }
  __syncthreads();
  {
    int p = t >> 5, nn = t & 31;
    float s1 = 0.f, s2 = 0.f;
    for (int j = 0; j < 32; j++){
      float v = x[p + 8 * j][nn];
      s1 += v; s2 += v * v;
    }
    ps[p][nn] = s1; ps2[p][nn] = s2;
  }
  __syncthreads();
  if (t < TN){
    float S1 = 0.f, S2 = 0.f;
    for (int pp = 0; pp < 8; pp++){ S1 += ps[pp][t]; S2 += ps2[pp][t]; }
    float mean = S1 * (1.f / C_);
    float var = S2 * (1.f / C_) - mean * mean;
    mean_s[t] = mean;
    rstd_s[t] = rsqrtf(var + 1e-5f);
  }
  __syncthreads();
  for (int k = 0; k < TN; k++){
    float sval = (x[t][k] - mean_s[k]) * rstd_s[k] * g_s[t] + bb_s[t];
    x[t][k] = sval;
  }
  for (int kq = 0; kq < TN; kq += 4){
    ushort4 pkv;
    pkv.x = f2bf(x[t][kq + 0]);
    pkv.y = f2bf(x[t][kq + 1]);
    pkv.z = f2bf(x[t][kq + 2]);
    pkv.w = f2bf(x[t][kq + 3]);
    *reinterpret_cast<ushort4*>(&srcT[(size_t)(b * C_ + t) * N_ + n0 + kq]) = pkv;
  }
  __syncthreads();
  {
    int p = t >> 5, nn = t & 31;
    float s2 = 0.f, sd = 0.f;
    for (int j = 0; j < 32; j++){
      int c = p + 8 * j;
      float v = x[c][nn];
      s2 += v * v; sd += v * tn_s[c];
    }
    ps[p][nn] = s2; ps2[p][nn] = sd;
  }
  __syncthreads();
  if (t < TN){
    float S2 = 0.f, SD = 0.f;
    for (int pp = 0; pp < 8; pp++){ S2 += ps[pp][t]; SD += ps2[pp][t]; }
    float nrm = sqrtf(S2);
    float rn = 1.f / fmaxf(nrm, 1e-12f);
    rn_s[t] = rn;
    cosv[(b << 12) + n0 + t] = SD * rn;
  }
  __syncthreads();
  for (int k = 0; k < TN; k++){
    snb[(size_t)((b << 12) + n0 + k) * C_ + t] = f2bf(x[t][k] * rn_s[k]);
  }
}

// ---------- marginals ----------
__global__ __launch_bounds__(256) void k_qmarg(const float* __restrict__ dens, float* __restrict__ q){
  int b = blockIdx.x, t = threadIdx.x;
  __shared__ float red[256];
  const float* d = dens + (size_t)b * N_;
  float s = 0.f;
  for (int n = t; n < N_; n += 256) s += fmaxf(d[n], 0.f) + 1e-6f;
  red[t] = s; __syncthreads();
  for (int o = 128; o > 0; o >>= 1){ if (t < o) red[t] += red[t + o]; __syncthreads(); }
  float inv = 1.f / red[0];
  for (int n = t; n < N_; n += 256) q[b * N_ + n] = (fmaxf(d[n], 0.f) + 1e-6f) * inv;
}

__global__ __launch_bounds__(256) void k_pmarg(const float* __restrict__ cosv,
    const float* __restrict__ temp_p, float* __restrict__ p){
  int b = blockIdx.x, t = threadIdx.x;
  __shared__ float red[256];
  float temp = fmaxf(temp_p[0], 0.01f);
  float inv_t = 1.f / temp;
  const float* cb = cosv + (size_t)b * N_;
  float m = -1e30f;
  for (int n = t; n < N_; n += 256) m = fmaxf(m, cb[n] * inv_t);
  red[t] = m; __syncthreads();
  for (int o = 128; o > 0; o >>= 1){ if (t < o) red[t] = fmaxf(red[t], red[t + o]); __syncthreads(); }
  m = red[0]; __syncthreads();
  float s = 0.f;
  for (int n = t; n < N_; n += 256) s += expf(cb[n] * inv_t - m);
  red[t] = s; __syncthreads();
  for (int o = 128; o > 0; o >>= 1){ if (t < o) red[t] += red[t + o]; __syncthreads(); }
  float invs = 1.f / red[0];
  for (int n = t; n < N_; n += 256) p[b * N_ + n] = expf(cb[n] * inv_t - m) * invs;
}

__global__ __launch_bounds__(256) void k_zero(float* __restrict__ p, int n){
  int i = blockIdx.x * 256 + threadIdx.x;
  if (i < n) p[i] = 0.f;
}

// ---------- K = exp(20*(sn sn^T - 1)) bf16 via MFMA, SYMMETRIC, two-pass epilogue ----------
__global__ __launch_bounds__(256) void k_kgen(
    const u16* __restrict__ snb, u16* __restrict__ Kp, float* __restrict__ colsum)
{
  int b = blockIdx.y;
  int kidx = blockIdx.x;
  int a = (int)((sqrtf(8.f * kidx + 1.f) - 1.f) * 0.5f);
  while ((a + 1) * (a + 2) / 2 <= kidx) a++;
  while (a * (a + 1) / 2 > kidx) a--;
  int bc = kidx - a * (a + 1) / 2;
  int n0 = a << 7, m0 = bc << 7;            // m0 <= n0
  bool diag = (m0 == n0);

  int t = threadIdx.x;
  int lane = t & 63, w = t >> 6;
  int wr = w >> 1, wc = w & 1;
  __shared__ __align__(16) u16 shbuf[128 * 128];    // 32 KB: Al|Bl, then Ct (twice)
  u16* Al = shbuf;
  u16* Bl = shbuf + 128 * 64;
  __shared__ float cs_col[128], cs_row[128];
  if (t < 128){ cs_col[t] = 0.f; cs_row[t] = 0.f; }
  f32x4 zero = {0.f, 0.f, 0.f, 0.f};
  f32x4 acc[4][4];
  #pragma unroll
  for (int i = 0; i < 4; i++){
    #pragma unroll
    for (int j = 0; j < 4; j++) acc[i][j] = zero;
  }
  const u16* sb = snb + (size_t)b * N_ * C_;
  const u16* ga = sb + (size_t)m0 * C_;
  const u16* gb = sb + (size_t)n0 * C_;
  const u16* Bsrc = diag ? Al : Bl;
  for (int kt = 0; kt < C_; kt += 64){
    stage_tile(ga + kt, C_, Al, t);
    if (!diag) stage_tile(gb + kt, C_, Bl, t);
    __syncthreads();
    #pragma unroll
    for (int kh = 0; kh < 2; kh++){
      short8 af[4], bfv[4];
      #pragma unroll
      for (int i = 0; i < 4; i++){
        af[i]  = frag_ld(Al,   wr * 64 + i * 16 + (lane & 15), kh * 4 + (lane >> 4));
        bfv[i] = frag_ld(Bsrc, wc * 64 + i * 16 + (lane & 15), kh * 4 + (lane >> 4));
      }
      #pragma unroll
      for (int i = 0; i < 4; i++){
        #pragma unroll
        for (int j = 0; j < 4; j++)
          acc[i][j] = MFMA_BF16(af[i], bfv[j], acc[i][j]);
      }
    }
    __syncthreads();
  }
  u16* Ct = shbuf;
  u16* Kb = Kp + (size_t)b * N_ * N_;
  // ---- pass 1: direct tile (rows m, cols n), col sums ----
  #pragma unroll
  for (int j = 0; j < 4; j++){
    int col = wc * 64 + j * 16 + (lane & 15);
    float csum = 0.f;
    #pragma unroll
    for (int i = 0; i < 4; i++){
      int rb = wr * 64 + i * 16 + (lane >> 4) * 4;
      #pragma unroll
      for (int r = 0; r < 4; r++){
        float e = expf(20.f * (acc[i][j][r] - 1.f));
        u16 pk = f2bf(e);
        csum += bf2f(pk);
        int row = rb + r;
        Ct[row * 128 + ((((col >> 3) ^ (row & 7)) << 3) | (col & 7))] = pk;
      }
    }
    atomicAdd(&cs_col[col], csum);
  }
  __syncthreads();
  for (int e = t; e < 2048; e += 256){
    int row = e >> 4, un = e & 15;
    short8 v8 = *(const short8*)(Ct + row * 128 + ((un ^ (row & 7)) << 3));
    *reinterpret_cast<short8*>(&Kb[(size_t)(m0 + row) * N_ + n0 + (un << 3)]) = v8;
  }
  // ---- pass 2: mirror tile; recompute exp, row sums computed here ----
  if (!diag){
    __syncthreads();
    #pragma unroll
    for (int i = 0; i < 4; i++){
      #pragma unroll
      for (int r = 0; r < 4; r++){
        int rowm = wr * 64 + i * 16 + (lane >> 4) * 4 + r;
        float s = 0.f;
        #pragma unroll
        for (int j = 0; j < 4; j++){
          int col = wc * 64 + j * 16 + (lane & 15);
          float e = expf(20.f * (acc[i][j][r] - 1.f));
          u16 pk = f2bf(e);
          s += bf2f(pk);
          Ct[col * 128 + ((((rowm >> 3) ^ (col & 7)) << 3) | (rowm & 7))] = pk;
        }
        s += __shfl_xor(s, 1); s += __shfl_xor(s, 2);
        s += __shfl_xor(s, 4); s += __shfl_xor(s, 8);
        if ((lane & 15) == 0) atomicAdd(&cs_row[rowm], s);
      }
    }
    __syncthreads();
    for (int e = t; e < 2048; e += 256){
      int c = e >> 4, un = e & 15;
      short8 v8 = *(const short8*)(Ct + c * 128 + ((un ^ (c & 7)) << 3));
      *reinterpret_cast<short8*>(&Kb[(size_t)(n0 + c) * N_ + m0 + (un << 3)]) = v8;
    }
  }
  if (t < 128){
    atomicAdd(&colsum[b * N_ + n0 + t], cs_col[t]);
    if (!diag) atomicAdd(&colsum[b * N_ + m0 + t], cs_row[t]);
  }
}

__global__ __launch_bounds__(256) void k_div(
    const float* __restrict__ marg, const float* __restrict__ denom, float* __restrict__ outp){
  int i = blockIdx.x * 256 + threadIdx.x;
  if (i < B_ * N_) outp[i] = marg[i] / (denom[i] + 1e-8f);
}

// ---------- out[r] = marg[r] / (K_row_r . x + 1e-8)  (K symmetric), 8 rows/block ----------
__global__ __launch_bounds__(256) void k_mv(
    const u16* __restrict__ Kp, const float* __restrict__ x,
    const float* __restrict__ marg, float* __restrict__ outp)
{
  int r0 = blockIdx.x * 8;
  int b = r0 >> 12;
  int t = threadIdx.x, w = t >> 6, lane = t & 63;
  __shared__ __align__(16) float xs[N_];
  const float* xb = x + b * N_;
  for (int i = t; i < N_ / 4; i += 256)
    reinterpret_cast<float4*>(xs)[i] = reinterpret_cast<const float4*>(xb)[i];
  __syncthreads();
  int r = r0 + w * 2;
  const u16* Kr0 = Kp + (size_t)b * N_ * N_ + (size_t)(r & (N_ - 1)) * N_;
  const u16* Kr1 = Kr0 + N_;
  float acc0 = 0.f, acc1 = 0.f;
  #pragma unroll
  for (int p = 0; p < 8; p++){
    int idx = p * 512 + lane * 8;
    short8 k0 = *reinterpret_cast<const short8*>(Kr0 + idx);
    short8 k1 = *reinterpret_cast<const short8*>(Kr1 + idx);
    float4 x0 = *reinterpret_cast<const float4*>(xs + idx);
    float4 x1 = *reinterpret_cast<const float4*>(xs + idx + 4);
    acc0 += bf2f((u16)k0[0]) * x0.x + bf2f((u16)k0[1]) * x0.y
          + bf2f((u16)k0[2]) * x0.z + bf2f((u16)k0[3]) * x0.w
          + bf2f((u16)k0[4]) * x1.x + bf2f((u16)k0[5]) * x1.y
          + bf2f((u16)k0[6]) * x1.z + bf2f((u16)k0[7]) * x1.w;
    acc1 += bf2f((u16)k1[0]) * x0.x + bf2f((u16)k1[1]) * x0.y
          + bf2f((u16)k1[2]) * x0.z + bf2f((u16)k1[3]) * x0.w
          + bf2f((u16)k1[4]) * x1.x + bf2f((u16)k1[5]) * x1.y
          + bf2f((u16)k1[6]) * x1.z + bf2f((u16)k1[7]) * x1.w;
  }
  for (int o = 32; o > 0; o >>= 1){
    acc0 += __shfl_down(acc0, o);
    acc1 += __shfl_down(acc1, o);
  }
  if (lane == 0){
    outp[r] = marg[r] / (acc0 + 1e-8f);
    outp[r + 1] = marg[r + 1] / (acc1 + 1e-8f);
  }
}

// ---------- usrcT[c][n] = srcT[c][n] * u[n] ----------
__global__ __launch_bounds__(256) void k_uscale(
    const u16* __restrict__ srcT, const float* __restrict__ uu, u16* __restrict__ usrcT)
{
  int i = blockIdx.x * 256 + threadIdx.x;
  int n8 = i & (N_ / 8 - 1);
  int row = i >> 9;
  int b = row >> 8;
  const u16* s = srcT + (size_t)row * N_ + n8 * 8;
  short8 v = *reinterpret_cast<const short8*>(s);
  const float* ub = uu + b * N_ + n8 * 8;
  short8 o;
  #pragma unroll
  for (int q = 0; q < 8; q++) o[q] = (short)f2bf(bf2f((u16)v[q]) * ub[q]);
  *reinterpret_cast<short8*>(usrcT + (size_t)row * N_ + n8 * 8) = o;
}

// ---------- part[ks][m][c] = vv[m] * sum_{n in ks chunk} K[m][n]*usrc[n][c] ----------
// 512 threads, tile 64m x 256c (full C in-block), 512 blocks, linear 32KB output stores.
__global__ __launch_bounds__(512) void k_full(
    const u16* __restrict__ Kp, const u16* __restrict__ usrcT,
    const float* __restrict__ vvv,
    u16* __restrict__ p0, u16* __restrict__ p1,
    u16* __restrict__ p2, u16* __restrict__ p3)
{
  int m0 = blockIdx.x << 6;
  int b = blockIdx.z >> 2, ks = blockIdx.z & 3;
  int t = threadIdx.x, lane = t & 63, w = t >> 6;   // w: 0..7 -> c-stripe of 32
  __shared__ __align__(16) u16 shbuf[64 * 64 + 256 * 64];  // Al 8KB | Bl 32KB
  __shared__ float vsm[64];
  u16* Al = shbuf;
  u16* Bl = shbuf + 64 * 64;
  if (t < 64) vsm[t] = vvv[b * N_ + m0 + t];
  f32x4 zero = {0.f, 0.f, 0.f, 0.f};
  f32x4 acc[4][2];
  #pragma unroll
  for (int i = 0; i < 4; i++){
    #pragma unroll
    for (int j = 0; j < 2; j++) acc[i][j] = zero;
  }
  const u16* ka = Kp + (size_t)b * N_ * N_ + (size_t)m0 * N_ + ks * (N_ / KSPLIT);
  const u16* ub = usrcT + (size_t)b * C_ * N_ + ks * (N_ / KSPLIT);
  for (int kt = 0; kt < N_ / KSPLIT; kt += 64){
    stage_tile512_64(ka + kt, N_, Al, t);
    stage_tile512_256(ub + kt, N_, Bl, t);
    __syncthreads();
    #pragma unroll
    for (int kh = 0; kh < 2; kh++){
      short8 af[4], bfv[2];
      #pragma unroll
      for (int i = 0; i < 4; i++)
        af[i] = frag_ld(Al, i * 16 + (lane & 15), kh * 4 + (lane >> 4));
      #pragma unroll
      for (int j = 0; j < 2; j++)
        bfv[j] = frag_ld(Bl, w * 32 + j * 16 + (lane & 15), kh * 4 + (lane >> 4));
      #pragma unroll
      for (int i = 0; i < 4; i++){
        #pragma unroll
        for (int j = 0; j < 2; j++)
          acc[i][j] = MFMA_BF16(af[i], bfv[j], acc[i][j]);
      }
    }
    __syncthreads();
  }
  // restage [64m][256c] bf16 (vv-scaled) into swizzled Ct, then fully-linear stores
  u16* Ct = shbuf;
  #pragma unroll
  for (int j = 0; j < 2; j++){
    int col = w * 32 + j * 16 + (lane & 15);
    #pragma unroll
    for (int i = 0; i < 4; i++){
      int rb = i * 16 + (lane >> 4) * 4;
      #pragma unroll
      for (int r = 0; r < 4; r++){
        int row = rb + r;
        Ct[row * 256 + ((((col >> 3) ^ (row & 7)) << 3) | (col & 7))] =
            f2bf(acc[i][j][r] * vsm[row]);
      }
    }
  }
  __syncthreads();
  u16* P = (ks == 0) ? p0 : (ks == 1) ? p1 : (ks == 2) ? p2 : p3;
  for (int e = t; e < 2048; e += 512){
    int row = e >> 5, un = e & 31;
    short8 v8 = *(const short8*)(Ct + row * 256 + ((un ^ (row & 7)) << 3));
    *reinterpret_cast<short8*>(&P[(size_t)((b << 12) + m0 + row) * C_ + (un << 3)]) = v8;
  }
}

// ---------- cast opw (f32 256x256) to bf16 ----------
__global__ __launch_bounds__(256) void k_wcast(const float* __restrict__ w, u16* __restrict__ o){
  int i = blockIdx.x * 256 + threadIdx.x;
  o[i] = f2bf(w[i]);
}

// ---------- out_feat = img + 1x1conv(p0+p1+p2+p3) via MFMA; tile 64n x 128co ----------
__global__ __launch_bounds__(256) void k_opconv(
    const u16* __restrict__ opwB, const float* __restrict__ opb,
    const u16* __restrict__ p0, const u16* __restrict__ p1,
    const u16* __restrict__ p2, const u16* __restrict__ p3,
    const float* __restrict__ img, float* __restrict__ outf)
{
  int b = blockIdx.z;
  int n0 = blockIdx.x << 6;
  int co0 = blockIdx.y << 7;
  int t = threadIdx.x, lane = t & 63, w = t >> 6;
  int wr = w >> 1, wc = w & 1;              // wr: co half (64), wc: n half (32)
  __shared__ __align__(16) u16 Al[128 * 64];   // opw rows=co
  __shared__ __align__(16) u16 Bl[64 * 64];    // fused rows=n
  f32x4 zero = {0.f, 0.f, 0.f, 0.f};
  f32x4 acc[4][2];
  #pragma unroll
  for (int i = 0; i < 4; i++){
    #pragma unroll
    for (int j = 0; j < 2; j++) acc[i][j] = zero;
  }
  for (int ct = 0; ct < C_; ct += 64){
    stage_tile(opwB + (size_t)co0 * C_ + ct, C_, Al, t);
    // reg-stage B: sum 4 bf16 partials into swizzled layout (512 units, 2 iters)
    #pragma unroll
    for (int q = 0; q < 2; q++){
      int e = q * 256 + t;
      int row = e >> 3, slot = e & 7;
      int col = ct + ((slot ^ (row & 7)) << 3);
      size_t idx = (size_t)((b << 12) + n0 + row) * C_ + col;
      short8 a0 = *reinterpret_cast<const short8*>(p0 + idx);
      short8 a1 = *reinterpret_cast<const short8*>(p1 + idx);
      short8 a2 = *reinterpret_cast<const short8*>(p2 + idx);
      short8 a3 = *reinterpret_cast<const short8*>(p3 + idx);
      short8 o;
      #pragma unroll
      for (int k = 0; k < 8; k++)
        o[k] = (short)f2bf(bf2f((u16)a0[k]) + bf2f((u16)a1[k]) + bf2f((u16)a2[k]) + bf2f((u16)a3[k]));
      *reinterpret_cast<short8*>(Bl + (size_t)e * 8) = o;
    }
    __syncthreads();
    #pragma unroll
    for (int kh = 0; kh < 2; kh++){
      short8 af[4], bfv[2];
      #pragma unroll
      for (int i = 0; i < 4; i++)
        af[i] = frag_ld(Al, wr * 64 + i * 16 + (lane & 15), kh * 4 + (lane >> 4));
      #pragma unroll
      for (int j = 0; j < 2; j++)
        bfv[j] = frag_ld(Bl, wc * 32 + j * 16 + (lane & 15), kh * 4 + (lane >> 4));
      #pragma unroll
      for (int i = 0; i < 4; i++){
        #pragma unroll
        for (int j = 0; j < 2; j++)
          acc[i][j] = MFMA_BF16(af[i], bfv[j], acc[i][j]);
      }
    }
    __syncthreads();
  }
  #pragma unroll
  for (int i = 0; i < 4; i++){
    int cb = co0 + wr * 64 + i * 16 + (lane >> 4) * 4;
    #pragma unroll
    for (int j = 0; j < 2; j++){
      int nc = n0 + wc * 32 + j * 16 + (lane & 15);
      #pragma unroll
      for (int r = 0; r < 4; r++){
        int co = cb + r;
        size_t oi = (size_t)(b * C_ + co) * N_ + nc;
        outf[oi] = acc[i][j][r] + img[oi] + opb[co];
      }
    }
  }
}

// ---------- transpose out_feat -> padded bf16 [b][px'][ci] ----------
__global__ __launch_bounds__(256) void k_tr(const float* __restrict__ outf, u16* __restrict__ inTp)
{
  int b = blockIdx.z;
  int c0 = blockIdx.y << 6;
  int px0 = blockIdx.x << 6;
  int t = threadIdx.x;
  __shared__ float tile[64][65];
  int tx = t & 63, ty4 = t >> 6;
  for (int cc = ty4; cc < 64; cc += 4)
    tile[cc][tx] = outf[((size_t)(b * C_) + c0 + cc) * N_ + px0 + tx];
  __syncthreads();
  int p = t >> 2, cg = (t & 3) << 4;
  int px = px0 + p;
  int y = px >> 6, x = px & 63;
  int pxp = y * 66 + x + 1;
  u16* dst = inTp + ((size_t)b * PXTOT + PXPAD + pxp) * C_ + c0 + cg;
  #pragma unroll
  for (int q = 0; q < 16; q += 4){
    ushort4 pk;
    pk.x = f2bf(tile[cg + q + 0][p]);
    pk.y = f2bf(tile[cg + q + 1][p]);
    pk.z = f2bf(tile[cg + q + 2][p]);
    pk.w = f2bf(tile[cg + q + 3][p]);
    *reinterpret_cast<ushort4*>(dst + q) = pk;
  }
}

// ---------- weights -> Wt[tap][co(256 fused)][ci] bf16, fused bias ----------
__global__ __launch_bounds__(256) void k_wtr(
    const float* __restrict__ hm1_w, const float* __restrict__ hv1_w,
    const float* __restrict__ hm1_b, const float* __restrict__ hv1_b,
    u16* __restrict__ Wt, float* __restrict__ biasF)
{
  int i = blockIdx.x * 256 + threadIdx.x;   // < 9*256*256
  int ci = i & 255, co = (i >> 8) & 255, tap = i >> 16;
  float v = (co < CH_) ? hm1_w[((size_t)co * C_ + ci) * 9 + tap]
                       : hv1_w[((size_t)(co - CH_) * C_ + ci) * 9 + tap];
  Wt[i] = f2bf(v);
  if (i < CH_) biasF[i] = hm1_b[i];
  else if (i < 2 * CH_) biasF[i] = hv1_b[i - CH_];
}

// ---------- fused 3x3 conv (both heads) as implicit GEMM: C[co][px'] (bf16 out) ----------
__global__ __launch_bounds__(256) void k_conv3m(
    const u16* __restrict__ inTp, const u16* __restrict__ Wt,
    const float* __restrict__ biasF,
    u16* __restrict__ q0, u16* __restrict__ q1,
    u16* __restrict__ q2, u16* __restrict__ q3)
{
  int px0 = blockIdx.x << 7;           // 0..32 (33 tiles of 128 px')
  int cot = blockIdx.y;                // 0..1 (co halves of 256 fused)
  int b = blockIdx.z >> 2, ks = blockIdx.z & 3;
  int t = threadIdx.x, lane = t & 63, w = t >> 6;
  int wr = w >> 1, wc = w & 1;
  __shared__ __align__(16) u16 Al[128 * 64];   // weights: 128 co rows x 64 ci
  __shared__ __align__(16) u16 Bl[128 * 64];   // input:   128 px rows x 64 ci
  f32x4 zero = {0.f, 0.f, 0.f, 0.f};
  f32x4 acc[4][4];
  #pragma unroll
  for (int i = 0; i < 4; i++){
    #pragma unroll
    for (int j = 0; j < 4; j++) acc[i][j] = zero;
  }
  const u16* inb = inTp + ((size_t)b * PXTOT + PXPAD + px0) * C_;
  for (int s = ks * 9; s < ks * 9 + 9; s++){
    int tap = s >> 2, cic = (s & 3) << 6;
    int ky = tap / 3, kx = tap - ky * 3;
    int off = (ky - 1) * 66 + (kx - 1);
    stage_tile(Wt + ((size_t)tap * 256 + cot * 128) * C_ + cic, C_, Al, t);
    stage_tile(inb + (ptrdiff_t)off * C_ + cic, C_, Bl, t);
    __syncthreads();
    #pragma unroll
    for (int kh = 0; kh < 2; kh++){
      short8 af[4], bfv[4];
      #pragma unroll
      for (int i = 0; i < 4; i++){
        af[i]  = frag_ld(Al, wr * 64 + i * 16 + (lane & 15), kh * 4 + (lane >> 4));
        bfv[i] = frag_ld(Bl, wc * 64 + i * 16 + (lane & 15), kh * 4 + (lane >> 4));
      }
      #pragma unroll
      for (int i = 0; i < 4; i++){
        #pragma unroll
        for (int j = 0; j < 4; j++)
          acc[i][j] = MFMA_BF16(af[i], bfv[j], acc[i][j]);
      }
    }
    __syncthreads();
  }
  u16* P = (ks == 0) ? q0 : (ks == 1) ? q1 : (ks == 2) ? q2 : q3;
  #pragma unroll
  for (int i = 0; i < 4; i++){
    #pragma unroll
    for (int j = 0; j < 4; j++){
      int pxp = px0 + wc * 64 + j * 16 + (lane & 15);
      int y = pxp / 66;
      int xm = pxp - y * 66;
      bool valid = (xm >= 1 && xm <= 64);
      int outn = y * 64 + xm - 1;
      #pragma unroll
      for (int r = 0; r < 4; r++){
        int co = cot * 128 + wr * 64 + i * 16 + (lane >> 4) * 4 + r;
        if (valid){
          float bco = (ks == 0) ? biasF[co] : 0.f;
          P[((size_t)(b * 256 + co)) * N_ + outn] = f2bf(acc[i][j][r] + bco);
        }
      }
    }
  }
}

// ---------- batchnorm stats over (B,H,W) per fused channel (sums 4 K-parts) ----------
__global__ __launch_bounds__(256) void k_bnstats2(
    const u16* __restrict__ p0, const u16* __restrict__ p1,
    const u16* __restrict__ p2, const u16* __restrict__ p3,
    float* __restrict__ stats)
{
  int ch = blockIdx.x, t = threadIdx.x;   // ch in [0,256)
  __shared__ float r1[256], r2[256];
  float s1 = 0.f, s2 = 0.f;
  for (int i = t; i < B_ * N_; i += 256){
    int b = i >> 12, n = i & (N_ - 1);
    size_t idx = ((size_t)(b * 256 + ch)) * N_ + n;
    float v = bf2f(p0[idx]) + bf2f(p1[idx]) + bf2f(p2[idx]) + bf2f(p3[idx]);
    s1 += v; s2 += v * v;
  }
  r1[t] = s1; r2[t] = s2; __syncthreads();
  for (int o = 128; o > 0; o >>= 1){
    if (t < o){ r1[t] += r1[t + o]; r2[t] += r2[t + o]; }
    __syncthreads();
  }
  if (t == 0){
    float mean = r1[0] / (float)(B_ * N_);
    float var = r2[0] / (float)(B_ * N_) - mean * mean;
    stats[ch * 2] = mean;
    stats[ch * 2 + 1] = rsqrtf(var + 1e-5f);
  }
}

// ---------- fused dual-head: relu(bn(mid)) -> 1x1 conv to 2 ch per head ----------
// 256 blocks x 256 threads: 32 n-slots x 8 ch-groups (g<4: hm, g>=4: hv).
__global__ __launch_bounds__(256) void k_headF(
    const u16* __restrict__ p0, const u16* __restrict__ p1,
    const u16* __restrict__ p2, const u16* __restrict__ p3,
    const float* __restrict__ stats,
    const float* __restrict__ hm_g, const float* __restrict__ hm_b,
    const float* __restrict__ hm2_w, const float* __restrict__ hm2_b,
    const float* __restrict__ hv_g, const float* __restrict__ hv_b,
    const float* __restrict__ hv2_w, const float* __restrict__ hv2_b,
    float* __restrict__ outhm, float* __restrict__ outhv)
{
  int t = threadIdx.x;
  int nl = t & 31, g = t >> 5;
  int idx0 = blockIdx.x * 32;
  int idx = idx0 + nl;
  int b = idx >> 12, n = idx & (N_ - 1);
  int head = g >> 2;
  int ch0 = (g & 3) * 32;
  const float* gg = head ? hv_g : hm_g;
  const float* gb = head ? hv_b : hm_b;
  const float* w2 = head ? hv2_w : hm2_w;
  float a0 = 0.f, a1 = 0.f;
  #pragma unroll 8
  for (int cc = 0; cc < 32; cc++){
    int ch = ch0 + cc;
    int fc = head * CH_ + ch;
    size_t id = ((size_t)(b * 256 + fc)) * N_ + n;
    float v = bf2f(p0[id]) + bf2f(p1[id]) + bf2f(p2[id]) + bf2f(p3[id]);
    float rr = fmaxf((v - stats[fc * 2]) * stats[fc * 2 + 1] * gg[ch] + gb[ch], 0.f);
    a0 += w2[ch] * rr;
    a1 += w2[CH_ + ch] * rr;
  }
  __shared__ float r0[8][32], r1[8][32];
  r0[g][nl] = a0; r1[g][nl] = a1;
  __syncthreads();
  if (t < 64){
    int hh = t >> 5, n2 = t & 31;
    int base = hh * 4;
    float s0 = r0[base][n2] + r0[base + 1][n2] + r0[base + 2][n2] + r0[base + 3][n2];
    float s1 = r1[base][n2] + r1[base + 1][n2] + r1[base + 2][n2] + r1[base + 3][n2];
    int idx2 = idx0 + n2;
    int b2 = idx2 >> 12, nn = idx2 & (N_ - 1);
    float* op = hh ? outhv : outhm;
    const float* bp = hh ? hv2_b : hm2_b;
    op[(size_t)(b2 * 2) * N_ + nn] = s0 + bp[0];
    op[(size_t)(b2 * 2 + 1) * N_ + nn] = s1 + bp[1];
  }
}

extern "C" void kernel_launch(void* const* d_in, const int* in_sizes, int n_in,
                              void* d_out, int out_size, void* d_ws, size_t ws_size,
                              hipStream_t stream)
{
  const float* img   = (const float*)d_in[0];
  const float* txt   = (const float*)d_in[1];
  const float* dens  = (const float*)d_in[2];
  const float* tp_w  = (const float*)d_in[3];
  const float* tp_b  = (const float*)d_in[4];
  const float* wv    = (const float*)d_in[9];
  const float* bv    = (const float*)d_in[10];
  const float* wo    = (const float*)d_in[11];
  const float* bo    = (const float*)d_in[12];
  const float* ln_g  = (const float*)d_in[13];
  const float* ln_b  = (const float*)d_in[14];
  const float* op_w  = (const float*)d_in[15];
  const float* op_b  = (const float*)d_in[16];
  const float* hm1_w = (const float*)d_in[17];
  const float* hm1_b = (const float*)d_in[18];
  const float* hm_g  = (const float*)d_in[19];
  const float* hm_b  = (const float*)d_in[20];
  const float* hm2_w = (const float*)d_in[21];
  const float* hm2_b = (const float*)d_in[22];
  const float* hv1_w = (const float*)d_in[23];
  const float* hv1_b = (const float*)d_in[24];
  const float* hv_g  = (const float*)d_in[25];
  const float* hv_b  = (const float*)d_in[26];
  const float* hv2_w = (const float*)d_in[27];
  const float* hv2_b = (const float*)d_in[28];
  const float* temp  = (const float*)d_in[29];

  char* wsb = (char*)d_ws;
  size_t off = 0;
  auto alloc = [&](size_t bytes) -> void* {
    void* p = wsb + off;
    off += (bytes + 255) & ~(size_t)255;
    return p;
  };
  u16*   Km     = (u16*)  alloc((size_t)B_ * N_ * N_ * sizeof(u16));   // 67.1 MB
  u16*   snb16  = (u16*)  alloc((size_t)B_ * N_ * C_ * sizeof(u16));   // 4.19 MB (part0 alias)
  u16*   srcT16 = (u16*)  alloc((size_t)B_ * C_ * N_ * sizeof(u16));   // 4.19 MB
  u16*   usrcT  = (u16*)  alloc((size_t)B_ * C_ * N_ * sizeof(u16));   // 4.19 MB
  u16*   part1  = (u16*)  alloc((size_t)B_ * N_ * C_ * sizeof(u16));   // 4.19 MB
  u16*   part2  = (u16*)  alloc((size_t)B_ * N_ * C_ * sizeof(u16));   // 4.19 MB
  u16*   part3  = (u16*)  alloc((size_t)B_ * N_ * C_ * sizeof(u16));   // 4.19 MB
  u16*   inTp   = (u16*)  alloc((size_t)B_ * PXTOT * C_ * sizeof(u16));// 4.52 MB
  u16*   Wt     = (u16*)  alloc((size_t)9 * 256 * C_ * sizeof(u16));   // 1.18 MB
  u16*   opwB   = (u16*)  alloc((size_t)C_ * C_ * sizeof(u16));        // 131 KB
  float* biasF  = (float*)alloc(256 * sizeof(float));
  float* txt_emb= (float*)alloc(B_ * C_ * sizeof(float));
  float* attn_c = (float*)alloc(B_ * C_ * sizeof(float));
  float* txt_n  = (float*)alloc(B_ * C_ * sizeof(float));
  float* cosv   = (float*)alloc(B_ * N_ * sizeof(float));
  float* qm     = (float*)alloc(B_ * N_ * sizeof(float));
  float* pm     = (float*)alloc(B_ * N_ * sizeof(float));
  float* uu     = (float*)alloc(B_ * N_ * sizeof(float));
  float* vvv    = (float*)alloc(B_ * N_ * sizeof(float));
  float* colsum = (float*)alloc(B_ * N_ * sizeof(float));
  float* stats  = (float*)alloc(256 * 2 * sizeof(float));

  // alias: part0 over snb16 (snb dead after kgen; part0 written by k_full)
  u16* part0 = snb16;

  float* outf  = (float*)d_out;
  float* outhm = outf + (size_t)B_ * C_ * N_;
  float* outhv = outhm + (size_t)B_ * 2 * N_;

  k_text<<<B_, 256, 0, stream>>>(txt, tp_w, tp_b, wv, bv, wo, bo, txt_emb, attn_c, txt_n);
  k_source<<<dim3(N_ / TN, B_), 256, 0, stream>>>(img, attn_c, ln_g, ln_b, txt_n, srcT16, snb16, cosv);
  k_qmarg<<<B_, 256, 0, stream>>>(dens, qm);
  k_pmarg<<<B_, 256, 0, stream>>>(cosv, temp, pm);
  k_zero<<<(B_ * N_ + 255) / 256, 256, 0, stream>>>(colsum, B_ * N_);
  // conv/opconv prep with no deps on GEMM chain
  k_wtr<<<9 * 256, 256, 0, stream>>>(hm1_w, hv1_w, hm1_b, hv1_b, Wt, biasF);
  k_wcast<<<C_ * C_ / 256, 256, 0, stream>>>(op_w, opwB);
  k_zero<<<((int)((size_t)B_ * PXTOT * C_ / 2) + 255) / 256, 256, 0, stream>>>((float*)inTp, (int)((size_t)B_ * PXTOT * C_ / 2));
  // symmetric K generation: 528 upper-triangular tile pairs per batch
  k_kgen<<<dim3(528, B_), 256, 0, stream>>>(snb16, Km, colsum);
  // Sinkhorn (K symmetric: K^T x == K x)
  k_div<<<(B_ * N_ + 255) / 256, 256, 0, stream>>>(qm, colsum, vvv);        // vv1
  k_mv<<<B_ * N_ / 8, 256, 0, stream>>>(Km, vvv, pm, uu);                   // u1
  k_mv<<<B_ * N_ / 8, 256, 0, stream>>>(Km, uu, qm, vvv);                   // vv2
  k_mv<<<B_ * N_ / 8, 256, 0, stream>>>(Km, vvv, pm, uu);                   // u2
  k_mv<<<B_ * N_ / 8, 256, 0, stream>>>(Km, uu, qm, vvv);                   // vv3
  k_mv<<<B_ * N_ / 8, 256, 0, stream>>>(Km, vvv, pm, uu);                   // u3
  k_uscale<<<(B_ * C_ * N_ / 8 + 255) / 256, 256, 0, stream>>>(srcT16, uu, usrcT);
  k_full<<<dim3(N_ / 64, 1, B_ * KSPLIT), 512, 0, stream>>>(Km, usrcT, vvv, part0, part1, part2, part3);
  k_opconv<<<dim3(N_ / 64, C_ / 128, B_), 256, 0, stream>>>(opwB, op_b, part0, part1, part2, part3, img, outf);
  // fused heads: transpose -> implicit-GEMM conv (both heads) -> BN stats -> heads
  k_tr<<<dim3(N_ / 64, 4, B_), 256, 0, stream>>>(outf, inTp);
  k_conv3m<<<dim3(33, 2, B_ * KSPLIT), 256, 0, stream>>>(inTp, Wt, biasF, part0, part1, part2, part3);
  k_bnstats2<<<256, 256, 0, stream>>>(part0, part1, part2, part3, stats);
  k_headF<<<B_ * N_ / 32, 256, 0, stream>>>(part0, part1, part2, part3, stats,
      hm_g, hm_b, hm2_w, hm2_b, hv_g, hv_b, hv2_w, hv2_b, outhm, outhv);
}